// Round 8
// baseline (233.287 us; speedup 1.0000x reference)
//
#include <hip/hip_runtime.h>
#include <hip/hip_bf16.h>

// GCN 2-layer: x[N,128] @ W1[128,64] -> agg(+relu) -> @ W2[64,32] -> agg -> out[N,32]
// CSR-by-dst via 2-level counting sort (R4/R5). bf16 intermediates (R6).
// gemm1 via MFMA 16x16x32 bf16 (R7).
// R8: channel-split + XCD-pinned aggregation. xws stored as 4 column-quarters
// (3.2MB each); agg1 pass q runs on XCD pair {2q,2q+1} (blockIdx%8 dispatch
// heuristic) so each XCD's 4MB L2 holds its whole quarter -> gather reuse
// (mean deg 16) becomes L2-hit instead of 42% L3 miss (R7: 87MB FETCH, 47us).
// agg2 likewise in 2 halves on XCD quads. Wrong-mapping risk: perf-neutral only.

#define C_IN  128
#define C_HID 64
#define C_OUT 32
#define BK_SHIFT 10
#define BK_NODES (1 << BK_SHIFT)
#define BK_MAXB  128
#define EPB 2048   // edges per bucket_edges block

typedef unsigned short ushort_t;
typedef __attribute__((ext_vector_type(8))) short bf16x8;
typedef __attribute__((ext_vector_type(4))) float f32x4;

__device__ inline ushort_t f2bf(float f) {
    __hip_bfloat16 b = __float2bfloat16(f);   // RNE
    return *reinterpret_cast<ushort_t*>(&b);
}
__device__ inline float bf2f(ushort_t u) {
    return __uint_as_float((unsigned int)u << 16);
}
__device__ inline float bflo(unsigned int v) { return __uint_as_float(v << 16); }
__device__ inline float bfhi(unsigned int v) { return __uint_as_float(v & 0xffff0000u); }

// ---------- CSR build ----------

// Phase A: partition edges into 1024-node dst buckets, bucket-major packed.
__global__ __launch_bounds__(256) void bucket_edges(
        const int* __restrict__ src, const int* __restrict__ dst,
        int* __restrict__ bcur, unsigned int* __restrict__ bucketed,
        int cap, int E, int nb) {
    __shared__ unsigned int stage[EPB];
    __shared__ unsigned char bkt[EPB];
    __shared__ int cnt[BK_MAXB];
    __shared__ int lofs[BK_MAXB];
    __shared__ int base[BK_MAXB];
    int tid = threadIdx.x;
    for (int i = tid; i < nb; i += 256) cnt[i] = 0;
    __syncthreads();
    int e0 = blockIdx.x * EPB;
    int myb[8]; int myr[8]; unsigned int mys[8];
    #pragma unroll
    for (int i = 0; i < 8; ++i) {
        int e = e0 + i * 256 + tid;
        if (e < E) {
            int d = dst[e];
            int s = src[e];
            int b = d >> BK_SHIFT;
            myb[i] = b;
            mys[i] = (unsigned int)s | ((unsigned int)(d & (BK_NODES - 1)) << 17);
            myr[i] = atomicAdd(&cnt[b], 1);
        } else myb[i] = -1;
    }
    __syncthreads();
    if (tid < 64) {
        int b0 = 2 * tid, b1 = 2 * tid + 1;
        int c0 = (b0 < nb) ? cnt[b0] : 0;
        int c1 = (b1 < nb) ? cnt[b1] : 0;
        int p = c0 + c1;
        int s = p;
        #pragma unroll
        for (int off = 1; off < 64; off <<= 1) {
            int t = __shfl_up(s, off, 64);
            if (tid >= off) s += t;
        }
        if (b0 < nb) lofs[b0] = s - p;
        if (b1 < nb) lofs[b1] = s - c1;
    }
    __syncthreads();
    #pragma unroll
    for (int i = 0; i < 8; ++i) {
        if (myb[i] >= 0) {
            int p = lofs[myb[i]] + myr[i];
            stage[p] = mys[i];
            bkt[p] = (unsigned char)myb[i];
        }
    }
    for (int i = tid; i < nb; i += 256)
        base[i] = atomicAdd(&bcur[i], cnt[i]);
    __syncthreads();
    int total = min(EPB, E - e0);
    for (int p = tid; p < total; p += 256) {
        int b = bkt[p];
        int di = base[b] + (p - lofs[b]);
        if (di < cap)
            bucketed[(size_t)b * cap + di] = stage[p];
    }
}

// Phase B1: per-bucket degree histogram in LDS -> coalesced deg writes.
__global__ __launch_bounds__(1024) void bucket_deg(
        const unsigned int* __restrict__ bucketed, const int* __restrict__ bcur,
        int* __restrict__ deg, int cap, int n) {
    __shared__ int lcur[BK_NODES];
    int b = blockIdx.x;
    int node0 = b << BK_SHIFT;
    int nn = min(BK_NODES, n - node0);
    for (int j = threadIdx.x; j < BK_NODES; j += 1024) lcur[j] = 0;
    __syncthreads();
    int cnt = min(bcur[b], cap);
    const unsigned int* bp = bucketed + (size_t)b * cap;
    for (int e = threadIdx.x; e < cnt; e += 1024)
        atomicAdd(&lcur[bp[e] >> 17], 1);
    __syncthreads();
    for (int j = threadIdx.x; j < nn; j += 1024)
        deg[node0 + j] = lcur[j];
}

// Phase B2: one block per bucket; LDS node cursors; writes confined to window.
__global__ __launch_bounds__(1024) void fill_csr_bucketed(
        const unsigned int* __restrict__ bucketed, const int* __restrict__ bcur,
        const int* __restrict__ offsets, int* __restrict__ csr_src, int cap, int n) {
    __shared__ int lcur[BK_NODES];
    int b = blockIdx.x;
    int node0 = b << BK_SHIFT;
    int nn = min(BK_NODES, n - node0);
    for (int j = threadIdx.x; j < nn; j += 1024)
        lcur[j] = offsets[node0 + j];
    __syncthreads();
    int cnt = min(bcur[b], cap);
    const unsigned int* bp = bucketed + (size_t)b * cap;
    for (int e = threadIdx.x; e < cnt; e += 1024) {
        unsigned int v = bp[e];
        int pos = atomicAdd(&lcur[v >> 17], 1);
        csr_src[pos] = (int)(v & 0x1FFFFu);
    }
}

// fallback path kernels
__global__ void count_deg(const int* __restrict__ dst, int* __restrict__ deg, int E) {
    int idx = blockIdx.x * blockDim.x + threadIdx.x;
    int stride = gridDim.x * blockDim.x;
    for (int e = idx; e < E; e += stride)
        atomicAdd(&deg[dst[e]], 1);
}

__global__ void fill_csr(const int* __restrict__ src, const int* __restrict__ dst,
                         int* __restrict__ cursor, int* __restrict__ csr_src, int E) {
    int idx = blockIdx.x * blockDim.x + threadIdx.x;
    int stride = gridDim.x * blockDim.x;
    for (int e = idx; e < E; e += stride) {
        int pos = atomicAdd(&cursor[dst[e]], 1);
        csr_src[pos] = src[e];
    }
}

// block-level exclusive scan; also emits dinv = rsqrt(deg+1)
__global__ void scan_blocks(const int* __restrict__ deg, int* __restrict__ offsets,
                            int* __restrict__ bsums, float* __restrict__ dinv, int n) {
    __shared__ int wsum[16];
    int tid = threadIdx.x, lane = tid & 63, wid = tid >> 6;
    int i = blockIdx.x * 1024 + tid;
    int v = (i < n) ? deg[i] : 0;
    if (i < n) dinv[i] = rsqrtf((float)v + 1.0f);
    int s = v;
    #pragma unroll
    for (int off = 1; off < 64; off <<= 1) {
        int t = __shfl_up(s, off, 64);
        if (lane >= off) s += t;
    }
    if (lane == 63) wsum[wid] = s;
    __syncthreads();
    if (wid == 0 && lane < 16) {
        int ws = wsum[lane];
        #pragma unroll
        for (int off = 1; off < 16; off <<= 1) {
            int t = __shfl_up(ws, off, 64);
            if (lane >= off) ws += t;
        }
        wsum[lane] = ws;
        if (lane == 15) bsums[blockIdx.x] = ws;
    }
    __syncthreads();
    int wpre = (wid > 0) ? wsum[wid - 1] : 0;
    if (i < n) offsets[i] = wpre + s - v;
}

__global__ void scan_bsums(int* __restrict__ bsums, int nb) {
    __shared__ int wsum[16];
    int tid = threadIdx.x, lane = tid & 63, wid = tid >> 6;
    int v = (tid < nb) ? bsums[tid] : 0;
    int s = v;
    #pragma unroll
    for (int off = 1; off < 64; off <<= 1) {
        int t = __shfl_up(s, off, 64);
        if (lane >= off) s += t;
    }
    if (lane == 63) wsum[wid] = s;
    __syncthreads();
    if (wid == 0 && lane < 16) {
        int ws = wsum[lane];
        #pragma unroll
        for (int off = 1; off < 16; off <<= 1) {
            int t = __shfl_up(ws, off, 64);
            if (lane >= off) ws += t;
        }
        wsum[lane] = ws;
    }
    __syncthreads();
    int wpre = (wid > 0) ? wsum[wid - 1] : 0;
    if (tid < nb) bsums[tid] = wpre + s - v;
}

__global__ void scan_add(int* __restrict__ offsets, const int* __restrict__ bsums,
                         int n, int E) {
    int i = blockIdx.x * 1024 + threadIdx.x;
    if (i < n) offsets[i] += bsums[blockIdx.x];
    if (i == 0) offsets[n] = E;
}

// ---------- gemm1: x[N,128] @ W1[128,64] via MFMA bf16, f32 accum ----------
// Output written COLUMN-QUARTERED: xwq[q][row][16] bf16 (quarter q = cols 16q..16q+15).
__global__ __launch_bounds__(256) void gemm1_mfma(
        const float* __restrict__ x, const float* __restrict__ W1,
        const float* __restrict__ dinv, ushort_t* __restrict__ xwq, int n) {
    __shared__ ushort_t Xs[64 * 136];      // padded row stride 136 (17408 B)
    __shared__ ushort_t Wl[16 * 64 * 8];   // [kblk][col][j] (16384 B)
    int tid = threadIdx.x;
    {
        const float4* Wv = reinterpret_cast<const float4*>(W1);  // 2048 float4
        #pragma unroll
        for (int p = 0; p < 8; ++p) {
            int idx = p * 256 + tid;
            float4 w = Wv[idx];
            int k = idx >> 4;            // 16 float4 per k-row (64 cols)
            int c0 = (idx & 15) * 4;
            ushort_t* d = &Wl[(k >> 3) * 512 + c0 * 8 + (k & 7)];
            d[0]  = f2bf(w.x);
            d[8]  = f2bf(w.y);
            d[16] = f2bf(w.z);
            d[24] = f2bf(w.w);
        }
    }
    int row0 = blockIdx.x * 64;
    {
        const float4* xv = reinterpret_cast<const float4*>(x + (size_t)row0 * C_IN);
        int maxv = min(64, n - row0) * (C_IN / 4);
        #pragma unroll
        for (int p = 0; p < 8; ++p) {
            int idx = p * 256 + tid;
            float4 v = (idx < maxv) ? xv[idx] : float4{0.f, 0.f, 0.f, 0.f};
            int row = idx >> 5, k4 = idx & 31;
            ushort4 pk;
            pk.x = f2bf(v.x); pk.y = f2bf(v.y); pk.z = f2bf(v.z); pk.w = f2bf(v.w);
            *reinterpret_cast<ushort4*>(&Xs[row * 136 + k4 * 4]) = pk;
        }
    }
    __syncthreads();
    int wid = tid >> 6, lane = tid & 63;
    int rbase = wid * 16;
    int l15 = lane & 15, kgrp = lane >> 4;
    f32x4 acc0 = {0.f, 0.f, 0.f, 0.f}, acc1 = acc0, acc2 = acc0, acc3 = acc0;
    #pragma unroll
    for (int kc = 0; kc < 4; ++kc) {
        bf16x8 a = *reinterpret_cast<const bf16x8*>(&Xs[(rbase + l15) * 136 + kc * 32 + kgrp * 8]);
        const ushort_t* wb = &Wl[(kc * 4 + kgrp) * 512 + l15 * 8];
        bf16x8 b0 = *reinterpret_cast<const bf16x8*>(wb);
        bf16x8 b1 = *reinterpret_cast<const bf16x8*>(wb + 128);
        bf16x8 b2 = *reinterpret_cast<const bf16x8*>(wb + 256);
        bf16x8 b3 = *reinterpret_cast<const bf16x8*>(wb + 384);
        acc0 = __builtin_amdgcn_mfma_f32_16x16x32_bf16(a, b0, acc0, 0, 0, 0);
        acc1 = __builtin_amdgcn_mfma_f32_16x16x32_bf16(a, b1, acc1, 0, 0, 0);
        acc2 = __builtin_amdgcn_mfma_f32_16x16x32_bf16(a, b2, acc2, 0, 0, 0);
        acc3 = __builtin_amdgcn_mfma_f32_16x16x32_bf16(a, b3, acc3, 0, 0, 0);
    }
    #pragma unroll
    for (int j = 0; j < 4; ++j) {
        int row = row0 + rbase + kgrp * 4 + j;
        if (row < n) {
            float di = dinv[row];
            xwq[((size_t)0 * n + row) * 16 + l15] = f2bf(di * acc0[j]);
            xwq[((size_t)1 * n + row) * 16 + l15] = f2bf(di * acc1[j]);
            xwq[((size_t)2 * n + row) * 16 + l15] = f2bf(di * acc2[j]);
            xwq[((size_t)3 * n + row) * 16 + l15] = f2bf(di * acc3[j]);
        }
    }
}

// ---------- gemm2 (f32 VALU, LDS-tiled; h bf16 in, xws2 bf16 HALVED out) ----------
// Output: x2h[h][row][16] bf16 (half h = cols 16h..16h+15).
__global__ __launch_bounds__(256) void gemm2(
        const ushort_t* __restrict__ h_bf, const float* __restrict__ W2,
        const float* __restrict__ dinv, ushort_t* __restrict__ x2h, int n) {
    __shared__ float Ws[C_HID * C_OUT];  // 8 KiB
    __shared__ float Hs[128 * C_HID];    // 32 KiB
    int tid = threadIdx.x;
    {
        const float4* Wv = reinterpret_cast<const float4*>(W2);
        float4* Wsv = reinterpret_cast<float4*>(Ws);
        #pragma unroll
        for (int p = 0; p < (C_HID * C_OUT / 4) / 256; ++p)
            Wsv[p * 256 + tid] = Wv[p * 256 + tid];
    }
    int row0 = blockIdx.x * 128;
    {
        const uint4* hv = reinterpret_cast<const uint4*>(h_bf + (size_t)row0 * C_HID);
        float4* Hsv = reinterpret_cast<float4*>(Hs);
        int maxe = min(128, n - row0) * (C_HID / 8);
        #pragma unroll
        for (int p = 0; p < 4; ++p) {
            int idx = p * 256 + tid;
            uint4 raw = (idx < maxe) ? hv[idx] : uint4{0u, 0u, 0u, 0u};
            float4 lo, hi;
            lo.x = bflo(raw.x); lo.y = bfhi(raw.x);
            lo.z = bflo(raw.y); lo.w = bfhi(raw.y);
            hi.x = bflo(raw.z); hi.y = bfhi(raw.z);
            hi.z = bflo(raw.w); hi.w = bfhi(raw.w);
            Hsv[idx * 2] = lo;
            Hsv[idx * 2 + 1] = hi;
        }
    }
    __syncthreads();
    int wid = tid >> 6, lane = tid & 63;
    int col = lane & 31, rh = lane >> 5;
    int rbase = wid * 32 + rh * 16;
    float acc[16];
    #pragma unroll
    for (int r = 0; r < 16; ++r) acc[r] = 0.f;
    const float4* Hsv = reinterpret_cast<const float4*>(Hs);
    int colh = col >> 4, cw = col & 15;
    #pragma unroll 2
    for (int k4 = 0; k4 < C_HID / 4; ++k4) {
        float w0 = Ws[(k4 * 4 + 0) * C_OUT + col];
        float w1 = Ws[(k4 * 4 + 1) * C_OUT + col];
        float w2 = Ws[(k4 * 4 + 2) * C_OUT + col];
        float w3 = Ws[(k4 * 4 + 3) * C_OUT + col];
        #pragma unroll
        for (int r = 0; r < 16; ++r) {
            float4 hv = Hsv[(rbase + r) * (C_HID / 4) + k4];
            acc[r] += hv.x * w0 + hv.y * w1 + hv.z * w2 + hv.w * w3;
        }
    }
    #pragma unroll
    for (int r = 0; r < 16; ++r) {
        int row = row0 + rbase + r;
        if (row < n)
            x2h[((size_t)colh * n + row) * 16 + cw] = f2bf(dinv[row] * acc[r]);
    }
}

// ---------- Aggregations: channel-split passes pinned to XCD groups ----------

// agg1: 4 quarter-passes; pass q on XCD pair {2q,2q+1} (blockIdx%8 heuristic).
// Wave: 8 edge slots (e=lane>>3) x 8 uint channel-pairs (c2=lane&7) = 16 ch.
__global__ __launch_bounds__(256) void agg1(
        const ushort_t* __restrict__ xwq, const float* __restrict__ dinv,
        const int* __restrict__ offsets, const int* __restrict__ csr_src,
        const float* __restrict__ b1, ushort_t* __restrict__ h_bf, int n) {
    int wid = threadIdx.x >> 6, lane = threadIdx.x & 63;
    int e = lane >> 3, c2 = lane & 7;
    int xcd = blockIdx.x & 7;
    int q = xcd >> 1;
    int lb = (blockIdx.x >> 3) * 2 + (xcd & 1);
    int stride = (gridDim.x >> 3) * 2 * 4;
    const unsigned int* xq = reinterpret_cast<const unsigned int*>(xwq) + (size_t)q * n * 8;
    unsigned int* hu = reinterpret_cast<unsigned int*>(h_bf);
    float2 bb = *reinterpret_cast<const float2*>(&b1[q * 16 + 2 * c2]);
    for (int i = lb * 4 + wid; i < n; i += stride) {
        int beg = offsets[i], end = offsets[i + 1];
        float di = dinv[i];
        float a0 = 0.f, a1 = 0.f;
        if (e == 0) {   // self-loop term, counted once
            unsigned int v = xq[(size_t)i * 8 + c2];
            a0 = bflo(v); a1 = bfhi(v);
        }
        int k = beg;
        for (; k + 16 <= end; k += 16) {
            int s0 = csr_src[k + e];
            int s1 = csr_src[k + 8 + e];
            unsigned int v0 = xq[(size_t)s0 * 8 + c2];
            unsigned int v1 = xq[(size_t)s1 * 8 + c2];
            a0 += bflo(v0) + bflo(v1);
            a1 += bfhi(v0) + bfhi(v1);
        }
        for (; k < end; k += 8) {
            int idx = k + e;
            if (idx < end) {
                int s = csr_src[idx];
                unsigned int v = xq[(size_t)s * 8 + c2];
                a0 += bflo(v); a1 += bfhi(v);
            }
        }
        a0 += __shfl_xor(a0, 8, 64);  a1 += __shfl_xor(a1, 8, 64);
        a0 += __shfl_xor(a0, 16, 64); a1 += __shfl_xor(a1, 16, 64);
        a0 += __shfl_xor(a0, 32, 64); a1 += __shfl_xor(a1, 32, 64);
        if (e == 0) {
            float r0 = fmaxf(di * a0 + bb.x, 0.f);
            float r1 = fmaxf(di * a1 + bb.y, 0.f);
            unsigned int pk = (unsigned int)f2bf(r0) | ((unsigned int)f2bf(r1) << 16);
            hu[(size_t)i * 32 + q * 8 + c2] = pk;   // h row-major [N][64]
        }
    }
}

// agg2: 2 half-passes; pass h2 on XCD quad. Same wave layout (16 ch per pass).
__global__ __launch_bounds__(256) void agg2(
        const ushort_t* __restrict__ x2h, const float* __restrict__ dinv,
        const int* __restrict__ offsets, const int* __restrict__ csr_src,
        const float* __restrict__ b2, float* __restrict__ out, int n) {
    int wid = threadIdx.x >> 6, lane = threadIdx.x & 63;
    int e = lane >> 3, c2 = lane & 7;
    int xcd = blockIdx.x & 7;
    int h2 = xcd >> 2;
    int lb = (blockIdx.x >> 3) * 4 + (xcd & 3);
    int stride = (gridDim.x >> 3) * 4 * 4;
    const unsigned int* xh = reinterpret_cast<const unsigned int*>(x2h) + (size_t)h2 * n * 8;
    float2* outv = reinterpret_cast<float2*>(out);
    float2 bb = *reinterpret_cast<const float2*>(&b2[h2 * 16 + 2 * c2]);
    for (int i = lb * 4 + wid; i < n; i += stride) {
        int beg = offsets[i], end = offsets[i + 1];
        float di = dinv[i];
        float a0 = 0.f, a1 = 0.f;
        if (e == 0) {
            unsigned int v = xh[(size_t)i * 8 + c2];
            a0 = bflo(v); a1 = bfhi(v);
        }
        int k = beg;
        for (; k + 16 <= end; k += 16) {
            int s0 = csr_src[k + e];
            int s1 = csr_src[k + 8 + e];
            unsigned int v0 = xh[(size_t)s0 * 8 + c2];
            unsigned int v1 = xh[(size_t)s1 * 8 + c2];
            a0 += bflo(v0) + bflo(v1);
            a1 += bfhi(v0) + bfhi(v1);
        }
        for (; k < end; k += 8) {
            int idx = k + e;
            if (idx < end) {
                int s = csr_src[idx];
                unsigned int v = xh[(size_t)s * 8 + c2];
                a0 += bflo(v); a1 += bfhi(v);
            }
        }
        a0 += __shfl_xor(a0, 8, 64);  a1 += __shfl_xor(a1, 8, 64);
        a0 += __shfl_xor(a0, 16, 64); a1 += __shfl_xor(a1, 16, 64);
        a0 += __shfl_xor(a0, 32, 64); a1 += __shfl_xor(a1, 32, 64);
        if (e == 0) {
            float2 r;
            r.x = di * a0 + bb.x;
            r.y = di * a1 + bb.y;
            outv[(size_t)i * 16 + h2 * 8 + c2] = r;   // out row-major [N][32] f32
        }
    }
}

extern "C" void kernel_launch(void* const* d_in, const int* in_sizes, int n_in,
                              void* d_out, int out_size, void* d_ws, size_t ws_size,
                              hipStream_t stream) {
    const float* x  = (const float*)d_in[0];
    const int*   ei = (const int*)d_in[1];
    const float* W1 = (const float*)d_in[2];
    const float* b1 = (const float*)d_in[3];
    const float* W2 = (const float*)d_in[4];
    const float* b2 = (const float*)d_in[5];
    float* out = (float*)d_out;

    const int N = in_sizes[0] / C_IN;      // 100000
    const int E = in_sizes[1] / 2;         // 1600000
    const int* src = ei;
    const int* dst = ei + E;

    const int NB = (N + BK_NODES - 1) >> BK_SHIFT;          // 98
    const int CAP = (2 * (E / NB) + 1023) & ~1023;          // 32768 (2x mean)

    char* ws = (char*)d_ws;
    size_t off = 0;
    auto alloc = [&](size_t bytes) { char* p = ws + off; off += (bytes + 255) & ~(size_t)255; return p; };
    ushort_t* xw_bf  = (ushort_t*)alloc((size_t)N * C_HID * 2);  // quartered xws / halved xws2
    ushort_t* h_bf   = (ushort_t*)alloc((size_t)N * C_HID * 2);
    int*   deg     = (int*)alloc((size_t)N * 4);
    float* dinv    = (float*)alloc((size_t)N * 4);
    int*   offsets = (int*)alloc((size_t)(N + 1) * 4);
    int*   cursor  = (int*)alloc((size_t)N * 4);
    int*   csr_src = (int*)alloc((size_t)E * 4);
    int*   bsums   = (int*)alloc(4096);
    int*   bcur    = (int*)alloc((size_t)BK_MAXB * 4);
    unsigned int* bucketed = (unsigned int*)alloc((size_t)NB * CAP * 4);
    bool use_bucket = (off <= ws_size) && (NB <= BK_MAXB) && (N < (1 << 17));

    const int nb1024 = (N + 1023) / 1024;  // 98

    if (use_bucket) {
        hipMemsetAsync(bcur, 0, (size_t)NB * 4, stream);
        bucket_edges<<<(E + EPB - 1) / EPB, 256, 0, stream>>>(
            src, dst, bcur, bucketed, CAP, E, NB);
        bucket_deg<<<NB, 1024, 0, stream>>>(bucketed, bcur, deg, CAP, N);
        scan_blocks<<<nb1024, 1024, 0, stream>>>(deg, offsets, bsums, dinv, N);
        scan_bsums<<<1, 1024, 0, stream>>>(bsums, nb1024);
        scan_add<<<nb1024, 1024, 0, stream>>>(offsets, bsums, N, E);
        fill_csr_bucketed<<<NB, 1024, 0, stream>>>(bucketed, bcur, offsets, csr_src, CAP, N);
    } else {
        hipMemsetAsync(deg, 0, (size_t)N * 4, stream);
        count_deg<<<2048, 256, 0, stream>>>(dst, deg, E);
        scan_blocks<<<nb1024, 1024, 0, stream>>>(deg, offsets, bsums, dinv, N);
        scan_bsums<<<1, 1024, 0, stream>>>(bsums, nb1024);
        scan_add<<<nb1024, 1024, 0, stream>>>(offsets, bsums, N, E);
        hipMemcpyAsync(cursor, offsets, (size_t)N * 4, hipMemcpyDeviceToDevice, stream);
        fill_csr<<<2048, 256, 0, stream>>>(src, dst, cursor, csr_src, E);
    }

    gemm1_mfma<<<(N + 63) / 64, 256, 0, stream>>>(x, W1, dinv, xw_bf, N);
    agg1<<<2048, 256, 0, stream>>>(xw_bf, dinv, offsets, csr_src, b1, h_bf, N);
    gemm2<<<(N + 127) / 128, 256, 0, stream>>>(h_bf, W2, dinv, xw_bf, N);
    agg2<<<2048, 256, 0, stream>>>(xw_bf, dinv, offsets, csr_src, b2, out, N);
}

// Round 9
// 170.797 us; speedup vs baseline: 1.3659x; 1.3659x over previous
//
#include <hip/hip_runtime.h>
#include <hip/hip_bf16.h>

// GCN 2-layer: x[N,128] @ W1[128,64] -> agg(+relu) -> @ W2[64,32] -> agg -> out[N,32]
// CSR-by-dst via 2-level counting sort (R4/R5). bf16 intermediates (R6).
// gemm1 via MFMA 16x16x32 bf16 (R7).
// R9: REVERT R8's channel-split (latency-bound kernel; 4x pass overhead doubled
// time despite lower FETCH). Instead: deepen MLP -- agg1 unrolled to 16 edges/
// iter (8 gathers in flight/wave), agg2 to 16 (4 in flight).

#define C_IN  128
#define C_HID 64
#define C_OUT 32
#define BK_SHIFT 10
#define BK_NODES (1 << BK_SHIFT)
#define BK_MAXB  128
#define EPB 2048   // edges per bucket_edges block

typedef unsigned short ushort_t;
typedef __attribute__((ext_vector_type(8))) short bf16x8;
typedef __attribute__((ext_vector_type(4))) float f32x4;

__device__ inline ushort_t f2bf(float f) {
    __hip_bfloat16 b = __float2bfloat16(f);   // RNE
    return *reinterpret_cast<ushort_t*>(&b);
}
__device__ inline float bf2f(ushort_t u) {
    return __uint_as_float((unsigned int)u << 16);
}
__device__ inline float bflo(unsigned int v) { return __uint_as_float(v << 16); }
__device__ inline float bfhi(unsigned int v) { return __uint_as_float(v & 0xffff0000u); }

// ---------- CSR build ----------

// Phase A: partition edges into 1024-node dst buckets, bucket-major packed.
__global__ __launch_bounds__(256) void bucket_edges(
        const int* __restrict__ src, const int* __restrict__ dst,
        int* __restrict__ bcur, unsigned int* __restrict__ bucketed,
        int cap, int E, int nb) {
    __shared__ unsigned int stage[EPB];
    __shared__ unsigned char bkt[EPB];
    __shared__ int cnt[BK_MAXB];
    __shared__ int lofs[BK_MAXB];
    __shared__ int base[BK_MAXB];
    int tid = threadIdx.x;
    for (int i = tid; i < nb; i += 256) cnt[i] = 0;
    __syncthreads();
    int e0 = blockIdx.x * EPB;
    int myb[8]; int myr[8]; unsigned int mys[8];
    #pragma unroll
    for (int i = 0; i < 8; ++i) {
        int e = e0 + i * 256 + tid;
        if (e < E) {
            int d = dst[e];
            int s = src[e];
            int b = d >> BK_SHIFT;
            myb[i] = b;
            mys[i] = (unsigned int)s | ((unsigned int)(d & (BK_NODES - 1)) << 17);
            myr[i] = atomicAdd(&cnt[b], 1);
        } else myb[i] = -1;
    }
    __syncthreads();
    if (tid < 64) {
        int b0 = 2 * tid, b1 = 2 * tid + 1;
        int c0 = (b0 < nb) ? cnt[b0] : 0;
        int c1 = (b1 < nb) ? cnt[b1] : 0;
        int p = c0 + c1;
        int s = p;
        #pragma unroll
        for (int off = 1; off < 64; off <<= 1) {
            int t = __shfl_up(s, off, 64);
            if (tid >= off) s += t;
        }
        if (b0 < nb) lofs[b0] = s - p;
        if (b1 < nb) lofs[b1] = s - c1;
    }
    __syncthreads();
    #pragma unroll
    for (int i = 0; i < 8; ++i) {
        if (myb[i] >= 0) {
            int p = lofs[myb[i]] + myr[i];
            stage[p] = mys[i];
            bkt[p] = (unsigned char)myb[i];
        }
    }
    for (int i = tid; i < nb; i += 256)
        base[i] = atomicAdd(&bcur[i], cnt[i]);
    __syncthreads();
    int total = min(EPB, E - e0);
    for (int p = tid; p < total; p += 256) {
        int b = bkt[p];
        int di = base[b] + (p - lofs[b]);
        if (di < cap)
            bucketed[(size_t)b * cap + di] = stage[p];
    }
}

// Phase B1: per-bucket degree histogram in LDS -> coalesced deg writes.
__global__ __launch_bounds__(1024) void bucket_deg(
        const unsigned int* __restrict__ bucketed, const int* __restrict__ bcur,
        int* __restrict__ deg, int cap, int n) {
    __shared__ int lcur[BK_NODES];
    int b = blockIdx.x;
    int node0 = b << BK_SHIFT;
    int nn = min(BK_NODES, n - node0);
    for (int j = threadIdx.x; j < BK_NODES; j += 1024) lcur[j] = 0;
    __syncthreads();
    int cnt = min(bcur[b], cap);
    const unsigned int* bp = bucketed + (size_t)b * cap;
    for (int e = threadIdx.x; e < cnt; e += 1024)
        atomicAdd(&lcur[bp[e] >> 17], 1);
    __syncthreads();
    for (int j = threadIdx.x; j < nn; j += 1024)
        deg[node0 + j] = lcur[j];
}

// Phase B2: one block per bucket; LDS node cursors; writes confined to window.
__global__ __launch_bounds__(1024) void fill_csr_bucketed(
        const unsigned int* __restrict__ bucketed, const int* __restrict__ bcur,
        const int* __restrict__ offsets, int* __restrict__ csr_src, int cap, int n) {
    __shared__ int lcur[BK_NODES];
    int b = blockIdx.x;
    int node0 = b << BK_SHIFT;
    int nn = min(BK_NODES, n - node0);
    for (int j = threadIdx.x; j < nn; j += 1024)
        lcur[j] = offsets[node0 + j];
    __syncthreads();
    int cnt = min(bcur[b], cap);
    const unsigned int* bp = bucketed + (size_t)b * cap;
    for (int e = threadIdx.x; e < cnt; e += 1024) {
        unsigned int v = bp[e];
        int pos = atomicAdd(&lcur[v >> 17], 1);
        csr_src[pos] = (int)(v & 0x1FFFFu);
    }
}

// fallback path kernels
__global__ void count_deg(const int* __restrict__ dst, int* __restrict__ deg, int E) {
    int idx = blockIdx.x * blockDim.x + threadIdx.x;
    int stride = gridDim.x * blockDim.x;
    for (int e = idx; e < E; e += stride)
        atomicAdd(&deg[dst[e]], 1);
}

__global__ void fill_csr(const int* __restrict__ src, const int* __restrict__ dst,
                         int* __restrict__ cursor, int* __restrict__ csr_src, int E) {
    int idx = blockIdx.x * blockDim.x + threadIdx.x;
    int stride = gridDim.x * blockDim.x;
    for (int e = idx; e < E; e += stride) {
        int pos = atomicAdd(&cursor[dst[e]], 1);
        csr_src[pos] = src[e];
    }
}

// block-level exclusive scan; also emits dinv = rsqrt(deg+1)
__global__ void scan_blocks(const int* __restrict__ deg, int* __restrict__ offsets,
                            int* __restrict__ bsums, float* __restrict__ dinv, int n) {
    __shared__ int wsum[16];
    int tid = threadIdx.x, lane = tid & 63, wid = tid >> 6;
    int i = blockIdx.x * 1024 + tid;
    int v = (i < n) ? deg[i] : 0;
    if (i < n) dinv[i] = rsqrtf((float)v + 1.0f);
    int s = v;
    #pragma unroll
    for (int off = 1; off < 64; off <<= 1) {
        int t = __shfl_up(s, off, 64);
        if (lane >= off) s += t;
    }
    if (lane == 63) wsum[wid] = s;
    __syncthreads();
    if (wid == 0 && lane < 16) {
        int ws = wsum[lane];
        #pragma unroll
        for (int off = 1; off < 16; off <<= 1) {
            int t = __shfl_up(ws, off, 64);
            if (lane >= off) ws += t;
        }
        wsum[lane] = ws;
        if (lane == 15) bsums[blockIdx.x] = ws;
    }
    __syncthreads();
    int wpre = (wid > 0) ? wsum[wid - 1] : 0;
    if (i < n) offsets[i] = wpre + s - v;
}

__global__ void scan_bsums(int* __restrict__ bsums, int nb) {
    __shared__ int wsum[16];
    int tid = threadIdx.x, lane = tid & 63, wid = tid >> 6;
    int v = (tid < nb) ? bsums[tid] : 0;
    int s = v;
    #pragma unroll
    for (int off = 1; off < 64; off <<= 1) {
        int t = __shfl_up(s, off, 64);
        if (lane >= off) s += t;
    }
    if (lane == 63) wsum[wid] = s;
    __syncthreads();
    if (wid == 0 && lane < 16) {
        int ws = wsum[lane];
        #pragma unroll
        for (int off = 1; off < 16; off <<= 1) {
            int t = __shfl_up(ws, off, 64);
            if (lane >= off) ws += t;
        }
        wsum[lane] = ws;
    }
    __syncthreads();
    int wpre = (wid > 0) ? wsum[wid - 1] : 0;
    if (tid < nb) bsums[tid] = wpre + s - v;
}

__global__ void scan_add(int* __restrict__ offsets, const int* __restrict__ bsums,
                         int n, int E) {
    int i = blockIdx.x * 1024 + threadIdx.x;
    if (i < n) offsets[i] += bsums[blockIdx.x];
    if (i == 0) offsets[n] = E;
}

// ---------- gemm1: x[N,128] @ W1[128,64] via MFMA bf16, f32 accum ----------
__global__ __launch_bounds__(256) void gemm1_mfma(
        const float* __restrict__ x, const float* __restrict__ W1,
        const float* __restrict__ dinv, ushort_t* __restrict__ xws_bf, int n) {
    __shared__ ushort_t Xs[64 * 136];      // padded row stride 136 (17408 B)
    __shared__ ushort_t Wl[16 * 64 * 8];   // [kblk][col][j] (16384 B)
    int tid = threadIdx.x;
    {
        const float4* Wv = reinterpret_cast<const float4*>(W1);  // 2048 float4
        #pragma unroll
        for (int p = 0; p < 8; ++p) {
            int idx = p * 256 + tid;
            float4 w = Wv[idx];
            int k = idx >> 4;            // 16 float4 per k-row (64 cols)
            int c0 = (idx & 15) * 4;
            ushort_t* d = &Wl[(k >> 3) * 512 + c0 * 8 + (k & 7)];
            d[0]  = f2bf(w.x);
            d[8]  = f2bf(w.y);
            d[16] = f2bf(w.z);
            d[24] = f2bf(w.w);
        }
    }
    int row0 = blockIdx.x * 64;
    {
        const float4* xv = reinterpret_cast<const float4*>(x + (size_t)row0 * C_IN);
        int maxv = min(64, n - row0) * (C_IN / 4);
        #pragma unroll
        for (int p = 0; p < 8; ++p) {
            int idx = p * 256 + tid;
            float4 v = (idx < maxv) ? xv[idx] : float4{0.f, 0.f, 0.f, 0.f};
            int row = idx >> 5, k4 = idx & 31;
            ushort4 pk;
            pk.x = f2bf(v.x); pk.y = f2bf(v.y); pk.z = f2bf(v.z); pk.w = f2bf(v.w);
            *reinterpret_cast<ushort4*>(&Xs[row * 136 + k4 * 4]) = pk;
        }
    }
    __syncthreads();
    int wid = tid >> 6, lane = tid & 63;
    int rbase = wid * 16;
    int l15 = lane & 15, kgrp = lane >> 4;
    f32x4 acc0 = {0.f, 0.f, 0.f, 0.f}, acc1 = acc0, acc2 = acc0, acc3 = acc0;
    #pragma unroll
    for (int kc = 0; kc < 4; ++kc) {
        bf16x8 a = *reinterpret_cast<const bf16x8*>(&Xs[(rbase + l15) * 136 + kc * 32 + kgrp * 8]);
        const ushort_t* wb = &Wl[(kc * 4 + kgrp) * 512 + l15 * 8];
        bf16x8 b0 = *reinterpret_cast<const bf16x8*>(wb);
        bf16x8 b1 = *reinterpret_cast<const bf16x8*>(wb + 128);
        bf16x8 b2 = *reinterpret_cast<const bf16x8*>(wb + 256);
        bf16x8 b3 = *reinterpret_cast<const bf16x8*>(wb + 384);
        acc0 = __builtin_amdgcn_mfma_f32_16x16x32_bf16(a, b0, acc0, 0, 0, 0);
        acc1 = __builtin_amdgcn_mfma_f32_16x16x32_bf16(a, b1, acc1, 0, 0, 0);
        acc2 = __builtin_amdgcn_mfma_f32_16x16x32_bf16(a, b2, acc2, 0, 0, 0);
        acc3 = __builtin_amdgcn_mfma_f32_16x16x32_bf16(a, b3, acc3, 0, 0, 0);
    }
    #pragma unroll
    for (int j = 0; j < 4; ++j) {
        int row = row0 + rbase + kgrp * 4 + j;
        if (row < n) {
            float di = dinv[row];
            ushort_t* o = &xws_bf[(size_t)row * C_HID + l15];
            o[0]  = f2bf(di * acc0[j]);
            o[16] = f2bf(di * acc1[j]);
            o[32] = f2bf(di * acc2[j]);
            o[48] = f2bf(di * acc3[j]);
        }
    }
}

// ---------- gemm2 (f32 VALU, LDS-tiled; h bf16 in, xws2 bf16 out) ----------

__global__ __launch_bounds__(256) void gemm2(
        const ushort_t* __restrict__ h_bf, const float* __restrict__ W2,
        const float* __restrict__ dinv, ushort_t* __restrict__ xws2_bf, int n) {
    __shared__ float Ws[C_HID * C_OUT];  // 8 KiB
    __shared__ float Hs[128 * C_HID];    // 32 KiB
    int tid = threadIdx.x;
    {
        const float4* Wv = reinterpret_cast<const float4*>(W2);
        float4* Wsv = reinterpret_cast<float4*>(Ws);
        #pragma unroll
        for (int p = 0; p < (C_HID * C_OUT / 4) / 256; ++p)
            Wsv[p * 256 + tid] = Wv[p * 256 + tid];
    }
    int row0 = blockIdx.x * 128;
    {
        const uint4* hv = reinterpret_cast<const uint4*>(h_bf + (size_t)row0 * C_HID);
        float4* Hsv = reinterpret_cast<float4*>(Hs);
        int maxe = min(128, n - row0) * (C_HID / 8);
        #pragma unroll
        for (int p = 0; p < 4; ++p) {
            int idx = p * 256 + tid;
            uint4 raw = (idx < maxe) ? hv[idx] : uint4{0u, 0u, 0u, 0u};
            float4 lo, hi;
            lo.x = bflo(raw.x); lo.y = bfhi(raw.x);
            lo.z = bflo(raw.y); lo.w = bfhi(raw.y);
            hi.x = bflo(raw.z); hi.y = bfhi(raw.z);
            hi.z = bflo(raw.w); hi.w = bfhi(raw.w);
            Hsv[idx * 2] = lo;
            Hsv[idx * 2 + 1] = hi;
        }
    }
    __syncthreads();
    int wid = tid >> 6, lane = tid & 63;
    int col = lane & 31, rh = lane >> 5;
    int rbase = wid * 32 + rh * 16;
    float acc[16];
    #pragma unroll
    for (int r = 0; r < 16; ++r) acc[r] = 0.f;
    const float4* Hsv = reinterpret_cast<const float4*>(Hs);
    #pragma unroll 2
    for (int k4 = 0; k4 < C_HID / 4; ++k4) {
        float w0 = Ws[(k4 * 4 + 0) * C_OUT + col];
        float w1 = Ws[(k4 * 4 + 1) * C_OUT + col];
        float w2 = Ws[(k4 * 4 + 2) * C_OUT + col];
        float w3 = Ws[(k4 * 4 + 3) * C_OUT + col];
        #pragma unroll
        for (int r = 0; r < 16; ++r) {
            float4 hv = Hsv[(rbase + r) * (C_HID / 4) + k4];
            acc[r] += hv.x * w0 + hv.y * w1 + hv.z * w2 + hv.w * w3;
        }
    }
    #pragma unroll
    for (int r = 0; r < 16; ++r) {
        int row = row0 + rbase + r;
        if (row < n) xws2_bf[(size_t)row * C_OUT + col] = f2bf(dinv[row] * acc[r]);
    }
}

// ---------- Aggregations: deep-MLP gathers, f32 accumulate ----------

// agg1: 2 edge slots (p=lane>>5) x 32 uint pairs (c2=lane&31); 16 edges/iter
// -> 8 gathers in flight per wave.
__global__ void agg1(const ushort_t* __restrict__ xws_bf, const float* __restrict__ dinv,
                     const int* __restrict__ offsets, const int* __restrict__ csr_src,
                     const float* __restrict__ b1, ushort_t* __restrict__ h_bf, int n) {
    int wid = threadIdx.x >> 6, lane = threadIdx.x & 63;
    int p = lane >> 5, c2 = lane & 31;
    const unsigned int* xu = reinterpret_cast<const unsigned int*>(xws_bf);
    float2 bb = *reinterpret_cast<const float2*>(&b1[2 * c2]);
    for (int i = blockIdx.x * 4 + wid; i < n; i += gridDim.x * 4) {
        int beg = offsets[i], end = offsets[i + 1];
        float di = dinv[i];
        float a0 = 0.f, a1 = 0.f;
        if (p == 0) {   // self-loop term counted once
            unsigned int v = xu[(size_t)i * 32 + c2];
            a0 = bflo(v); a1 = bfhi(v);
        }
        int k = beg;
        for (; k + 16 <= end; k += 16) {
            int s0 = csr_src[k + p];
            int s1 = csr_src[k + 2 + p];
            int s2 = csr_src[k + 4 + p];
            int s3 = csr_src[k + 6 + p];
            int s4 = csr_src[k + 8 + p];
            int s5 = csr_src[k + 10 + p];
            int s6 = csr_src[k + 12 + p];
            int s7 = csr_src[k + 14 + p];
            unsigned int v0 = xu[(size_t)s0 * 32 + c2];
            unsigned int v1 = xu[(size_t)s1 * 32 + c2];
            unsigned int v2 = xu[(size_t)s2 * 32 + c2];
            unsigned int v3 = xu[(size_t)s3 * 32 + c2];
            unsigned int v4 = xu[(size_t)s4 * 32 + c2];
            unsigned int v5 = xu[(size_t)s5 * 32 + c2];
            unsigned int v6 = xu[(size_t)s6 * 32 + c2];
            unsigned int v7 = xu[(size_t)s7 * 32 + c2];
            a0 += ((bflo(v0) + bflo(v1)) + (bflo(v2) + bflo(v3)))
                + ((bflo(v4) + bflo(v5)) + (bflo(v6) + bflo(v7)));
            a1 += ((bfhi(v0) + bfhi(v1)) + (bfhi(v2) + bfhi(v3)))
                + ((bfhi(v4) + bfhi(v5)) + (bfhi(v6) + bfhi(v7)));
        }
        for (; k + 8 <= end; k += 8) {
            int s0 = csr_src[k + p];
            int s1 = csr_src[k + 2 + p];
            int s2 = csr_src[k + 4 + p];
            int s3 = csr_src[k + 6 + p];
            unsigned int v0 = xu[(size_t)s0 * 32 + c2];
            unsigned int v1 = xu[(size_t)s1 * 32 + c2];
            unsigned int v2 = xu[(size_t)s2 * 32 + c2];
            unsigned int v3 = xu[(size_t)s3 * 32 + c2];
            a0 += (bflo(v0) + bflo(v1)) + (bflo(v2) + bflo(v3));
            a1 += (bfhi(v0) + bfhi(v1)) + (bfhi(v2) + bfhi(v3));
        }
        for (; k + 2 <= end; k += 2) {
            int s = csr_src[k + p];
            unsigned int v = xu[(size_t)s * 32 + c2];
            a0 += bflo(v); a1 += bfhi(v);
        }
        if (k < end && p == 0) {   // odd tail
            int s = csr_src[k];
            unsigned int v = xu[(size_t)s * 32 + c2];
            a0 += bflo(v); a1 += bfhi(v);
        }
        a0 += __shfl_xor(a0, 32, 64);
        a1 += __shfl_xor(a1, 32, 64);
        if (p == 0) {
            float r0 = fmaxf(di * a0 + bb.x, 0.f);
            float r1 = fmaxf(di * a1 + bb.y, 0.f);
            unsigned int pk = (unsigned int)f2bf(r0) | ((unsigned int)f2bf(r1) << 16);
            *reinterpret_cast<unsigned int*>(&h_bf[(size_t)i * C_HID + 2 * c2]) = pk;
        }
    }
}

// agg2: 4 edge slots (q=lane>>4) x 16 uint pairs (c2=lane&15); 16 edges/iter
// -> 4 gathers in flight per wave.
__global__ void agg2(const ushort_t* __restrict__ xws2_bf, const float* __restrict__ dinv,
                     const int* __restrict__ offsets, const int* __restrict__ csr_src,
                     const float* __restrict__ b2, float* __restrict__ out, int n) {
    int wid = threadIdx.x >> 6, lane = threadIdx.x & 63;
    int q = lane >> 4, c2 = lane & 15;
    const unsigned int* xu = reinterpret_cast<const unsigned int*>(xws2_bf);
    float2 bb = *reinterpret_cast<const float2*>(&b2[2 * c2]);
    for (int i = blockIdx.x * 4 + wid; i < n; i += gridDim.x * 4) {
        int beg = offsets[i], end = offsets[i + 1];
        float di = dinv[i];
        float a0 = 0.f, a1 = 0.f;
        if (q == 0) {
            unsigned int v = xu[(size_t)i * 16 + c2];
            a0 = bflo(v); a1 = bfhi(v);
        }
        int k = beg;
        for (; k + 16 <= end; k += 16) {
            int s0 = csr_src[k + q];
            int s1 = csr_src[k + 4 + q];
            int s2 = csr_src[k + 8 + q];
            int s3 = csr_src[k + 12 + q];
            unsigned int v0 = xu[(size_t)s0 * 16 + c2];
            unsigned int v1 = xu[(size_t)s1 * 16 + c2];
            unsigned int v2 = xu[(size_t)s2 * 16 + c2];
            unsigned int v3 = xu[(size_t)s3 * 16 + c2];
            a0 += (bflo(v0) + bflo(v1)) + (bflo(v2) + bflo(v3));
            a1 += (bfhi(v0) + bfhi(v1)) + (bfhi(v2) + bfhi(v3));
        }
        for (; k + 8 <= end; k += 8) {
            int s0 = csr_src[k + q];
            int s1 = csr_src[k + 4 + q];
            unsigned int v0 = xu[(size_t)s0 * 16 + c2];
            unsigned int v1 = xu[(size_t)s1 * 16 + c2];
            a0 += bflo(v0) + bflo(v1);
            a1 += bfhi(v0) + bfhi(v1);
        }
        for (; k + 4 <= end; k += 4) {
            int s = csr_src[k + q];
            unsigned int v = xu[(size_t)s * 16 + c2];
            a0 += bflo(v); a1 += bfhi(v);
        }
        if (k + q < end) {   // tail 1..3 edges
            int s = csr_src[k + q];
            unsigned int v = xu[(size_t)s * 16 + c2];
            a0 += bflo(v); a1 += bfhi(v);
        }
        a0 += __shfl_xor(a0, 32, 64);
        a0 += __shfl_xor(a0, 16, 64);
        a1 += __shfl_xor(a1, 32, 64);
        a1 += __shfl_xor(a1, 16, 64);
        if (q == 0) {
            float2 r;
            r.x = di * a0 + bb.x;
            r.y = di * a1 + bb.y;
            *reinterpret_cast<float2*>(&out[(size_t)i * C_OUT + 2 * c2]) = r;
        }
    }
}

extern "C" void kernel_launch(void* const* d_in, const int* in_sizes, int n_in,
                              void* d_out, int out_size, void* d_ws, size_t ws_size,
                              hipStream_t stream) {
    const float* x  = (const float*)d_in[0];
    const int*   ei = (const int*)d_in[1];
    const float* W1 = (const float*)d_in[2];
    const float* b1 = (const float*)d_in[3];
    const float* W2 = (const float*)d_in[4];
    const float* b2 = (const float*)d_in[5];
    float* out = (float*)d_out;

    const int N = in_sizes[0] / C_IN;      // 100000
    const int E = in_sizes[1] / 2;         // 1600000
    const int* src = ei;
    const int* dst = ei + E;

    const int NB = (N + BK_NODES - 1) >> BK_SHIFT;          // 98
    const int CAP = (2 * (E / NB) + 1023) & ~1023;          // 32768 (2x mean)

    char* ws = (char*)d_ws;
    size_t off = 0;
    auto alloc = [&](size_t bytes) { char* p = ws + off; off += (bytes + 255) & ~(size_t)255; return p; };
    ushort_t* xw_bf  = (ushort_t*)alloc((size_t)N * C_HID * 2);  // xws1, reused as xws2
    ushort_t* h_bf   = (ushort_t*)alloc((size_t)N * C_HID * 2);
    int*   deg     = (int*)alloc((size_t)N * 4);
    float* dinv    = (float*)alloc((size_t)N * 4);
    int*   offsets = (int*)alloc((size_t)(N + 1) * 4);
    int*   cursor  = (int*)alloc((size_t)N * 4);
    int*   csr_src = (int*)alloc((size_t)E * 4);
    int*   bsums   = (int*)alloc(4096);
    int*   bcur    = (int*)alloc((size_t)BK_MAXB * 4);
    unsigned int* bucketed = (unsigned int*)alloc((size_t)NB * CAP * 4);
    bool use_bucket = (off <= ws_size) && (NB <= BK_MAXB) && (N < (1 << 17));

    const int nb1024 = (N + 1023) / 1024;  // 98

    if (use_bucket) {
        hipMemsetAsync(bcur, 0, (size_t)NB * 4, stream);
        bucket_edges<<<(E + EPB - 1) / EPB, 256, 0, stream>>>(
            src, dst, bcur, bucketed, CAP, E, NB);
        bucket_deg<<<NB, 1024, 0, stream>>>(bucketed, bcur, deg, CAP, N);
        scan_blocks<<<nb1024, 1024, 0, stream>>>(deg, offsets, bsums, dinv, N);
        scan_bsums<<<1, 1024, 0, stream>>>(bsums, nb1024);
        scan_add<<<nb1024, 1024, 0, stream>>>(offsets, bsums, N, E);
        fill_csr_bucketed<<<NB, 1024, 0, stream>>>(bucketed, bcur, offsets, csr_src, CAP, N);
    } else {
        hipMemsetAsync(deg, 0, (size_t)N * 4, stream);
        count_deg<<<2048, 256, 0, stream>>>(dst, deg, E);
        scan_blocks<<<nb1024, 1024, 0, stream>>>(deg, offsets, bsums, dinv, N);
        scan_bsums<<<1, 1024, 0, stream>>>(bsums, nb1024);
        scan_add<<<nb1024, 1024, 0, stream>>>(offsets, bsums, N, E);
        hipMemcpyAsync(cursor, offsets, (size_t)N * 4, hipMemcpyDeviceToDevice, stream);
        fill_csr<<<2048, 256, 0, stream>>>(src, dst, cursor, csr_src, E);
    }

    gemm1_mfma<<<(N + 63) / 64, 256, 0, stream>>>(x, W1, dinv, xw_bf, N);
    agg1<<<2048, 256, 0, stream>>>(xw_bf, dinv, offsets, csr_src, b1, h_bf, N);
    gemm2<<<(N + 127) / 128, 256, 0, stream>>>(h_bf, W2, dinv, xw_bf, N);
    agg2<<<2048, 256, 0, stream>>>(xw_bf, dinv, offsets, csr_src, b2, out, N);
}

// Round 10
// 149.036 us; speedup vs baseline: 1.5653x; 1.1460x over previous
//
#include <hip/hip_runtime.h>
#include <hip/hip_bf16.h>

// GCN 2-layer: x[N,128] @ W1[128,64] -> agg(+relu) -> @ W2[64,32] -> agg -> out[N,32]
// CSR-by-dst via 2-level counting sort (R4/R5). bf16 intermediates (R6).
// gemm1 via MFMA 16x16x32 bf16 (R7). Deep-MLP aggs (R9).
// R10: (a) agg1 = one node per HALF-wave (32 lanes x uint = 64ch), agg2 = one
//      node per QUARTER-wave -- no shuffles, no write guards, 2x/4x independent
//      nodes per wave so gather bursts overlap (R9 lesson: per-node burst+dribble
//      capped avg MLP).
//      (b) fused CSR: scan_eb (98-entry bucket prefix) + fill_csr_fused
//      (LDS histogram -> LDS scan -> offsets/dinv -> LDS-cursor fill) replaces
//      bucket_deg + 3 scan kernels + deg array.

#define C_IN  128
#define C_HID 64
#define C_OUT 32
#define BK_SHIFT 10
#define BK_NODES (1 << BK_SHIFT)
#define BK_MAXB  128
#define EPB 2048   // edges per bucket_edges block

typedef unsigned short ushort_t;
typedef __attribute__((ext_vector_type(8))) short bf16x8;
typedef __attribute__((ext_vector_type(4))) float f32x4;

__device__ inline ushort_t f2bf(float f) {
    __hip_bfloat16 b = __float2bfloat16(f);   // RNE
    return *reinterpret_cast<ushort_t*>(&b);
}
__device__ inline float bflo(unsigned int v) { return __uint_as_float(v << 16); }
__device__ inline float bfhi(unsigned int v) { return __uint_as_float(v & 0xffff0000u); }

// ---------- CSR build ----------

// Phase A: partition edges into 1024-node dst buckets, bucket-major packed.
__global__ __launch_bounds__(256) void bucket_edges(
        const int* __restrict__ src, const int* __restrict__ dst,
        int* __restrict__ bcur, unsigned int* __restrict__ bucketed,
        int cap, int E, int nb) {
    __shared__ unsigned int stage[EPB];
    __shared__ unsigned char bkt[EPB];
    __shared__ int cnt[BK_MAXB];
    __shared__ int lofs[BK_MAXB];
    __shared__ int base[BK_MAXB];
    int tid = threadIdx.x;
    for (int i = tid; i < nb; i += 256) cnt[i] = 0;
    __syncthreads();
    int e0 = blockIdx.x * EPB;
    int myb[8]; int myr[8]; unsigned int mys[8];
    #pragma unroll
    for (int i = 0; i < 8; ++i) {
        int e = e0 + i * 256 + tid;
        if (e < E) {
            int d = dst[e];
            int s = src[e];
            int b = d >> BK_SHIFT;
            myb[i] = b;
            mys[i] = (unsigned int)s | ((unsigned int)(d & (BK_NODES - 1)) << 17);
            myr[i] = atomicAdd(&cnt[b], 1);
        } else myb[i] = -1;
    }
    __syncthreads();
    if (tid < 64) {
        int b0 = 2 * tid, b1 = 2 * tid + 1;
        int c0 = (b0 < nb) ? cnt[b0] : 0;
        int c1 = (b1 < nb) ? cnt[b1] : 0;
        int p = c0 + c1;
        int s = p;
        #pragma unroll
        for (int off = 1; off < 64; off <<= 1) {
            int t = __shfl_up(s, off, 64);
            if (tid >= off) s += t;
        }
        if (b0 < nb) lofs[b0] = s - p;
        if (b1 < nb) lofs[b1] = s - c1;
    }
    __syncthreads();
    #pragma unroll
    for (int i = 0; i < 8; ++i) {
        if (myb[i] >= 0) {
            int p = lofs[myb[i]] + myr[i];
            stage[p] = mys[i];
            bkt[p] = (unsigned char)myb[i];
        }
    }
    for (int i = tid; i < nb; i += 256)
        base[i] = atomicAdd(&bcur[i], cnt[i]);
    __syncthreads();
    int total = min(EPB, E - e0);
    for (int p = tid; p < total; p += 256) {
        int b = bkt[p];
        int di = base[b] + (p - lofs[b]);
        if (di < cap)
            bucketed[(size_t)b * cap + di] = stage[p];
    }
}

// exclusive scan of per-bucket counts (nb <= 128); also writes offsets[n].
__global__ void scan_eb(const int* __restrict__ bcur, int* __restrict__ ebase,
                        int* __restrict__ offsets, int cap, int nb, int n) {
    __shared__ int wsum[2];
    int tid = threadIdx.x;           // 128 threads
    int lane = tid & 63, wid = tid >> 6;
    int v = (tid < nb) ? min(bcur[tid], cap) : 0;
    int s = v;
    #pragma unroll
    for (int off = 1; off < 64; off <<= 1) {
        int t = __shfl_up(s, off, 64);
        if (lane >= off) s += t;
    }
    if (lane == 63) wsum[wid] = s;
    __syncthreads();
    int incl = s + ((wid == 1) ? wsum[0] : 0);
    if (tid < nb) ebase[tid] = incl - v;
    if (tid == nb - 1) { ebase[nb] = incl; offsets[n] = incl; }
}

// Fused per-bucket: LDS degree histogram -> LDS scan -> offsets+dinv writes ->
// LDS-cursor csr fill. One block per bucket; all csr writes land in the
// bucket's contiguous window.
__global__ __launch_bounds__(1024) void fill_csr_fused(
        const unsigned int* __restrict__ bucketed, const int* __restrict__ ebase,
        int* __restrict__ offsets, float* __restrict__ dinv,
        int* __restrict__ csr_src, int cap, int n) {
    __shared__ int hist[BK_NODES];
    __shared__ int wsum[16];
    int tid = threadIdx.x, lane = tid & 63, wid = tid >> 6;
    int b = blockIdx.x;
    int node0 = b << BK_SHIFT;
    int nn = min(BK_NODES, n - node0);
    int eb = ebase[b];
    int cnt = ebase[b + 1] - eb;
    const unsigned int* bp = bucketed + (size_t)b * cap;
    hist[tid] = 0;
    __syncthreads();
    for (int e = tid; e < cnt; e += 1024)
        atomicAdd(&hist[bp[e] >> 17], 1);
    __syncthreads();
    int v = hist[tid];
    int s = v;
    #pragma unroll
    for (int off = 1; off < 64; off <<= 1) {
        int t = __shfl_up(s, off, 64);
        if (lane >= off) s += t;
    }
    if (lane == 63) wsum[wid] = s;
    __syncthreads();
    if (wid == 0 && lane < 16) {
        int ws = wsum[lane];
        #pragma unroll
        for (int off = 1; off < 16; off <<= 1) {
            int t = __shfl_up(ws, off, 64);
            if (lane >= off) ws += t;
        }
        wsum[lane] = ws;
    }
    __syncthreads();
    int wpre = (wid > 0) ? wsum[wid - 1] : 0;
    int excl = wpre + s - v;           // exclusive degree prefix within bucket
    if (tid < nn) {
        offsets[node0 + tid] = eb + excl;
        dinv[node0 + tid] = rsqrtf((float)v + 1.0f);
    }
    __syncthreads();                   // all hist/wsum reads done
    hist[tid] = eb + excl;             // cursor
    __syncthreads();
    for (int e = tid; e < cnt; e += 1024) {
        unsigned int u = bp[e];
        int pos = atomicAdd(&hist[u >> 17], 1);
        csr_src[pos] = (int)(u & 0x1FFFFu);
    }
}

// ---- fallback path kernels (unused when workspace suffices) ----
__global__ void count_deg(const int* __restrict__ dst, int* __restrict__ deg, int E) {
    int idx = blockIdx.x * blockDim.x + threadIdx.x;
    int stride = gridDim.x * blockDim.x;
    for (int e = idx; e < E; e += stride)
        atomicAdd(&deg[dst[e]], 1);
}

__global__ void fill_csr(const int* __restrict__ src, const int* __restrict__ dst,
                         int* __restrict__ cursor, int* __restrict__ csr_src, int E) {
    int idx = blockIdx.x * blockDim.x + threadIdx.x;
    int stride = gridDim.x * blockDim.x;
    for (int e = idx; e < E; e += stride) {
        int pos = atomicAdd(&cursor[dst[e]], 1);
        csr_src[pos] = src[e];
    }
}

__global__ void scan_blocks(const int* __restrict__ deg, int* __restrict__ offsets,
                            int* __restrict__ bsums, float* __restrict__ dinv, int n) {
    __shared__ int wsum[16];
    int tid = threadIdx.x, lane = tid & 63, wid = tid >> 6;
    int i = blockIdx.x * 1024 + tid;
    int v = (i < n) ? deg[i] : 0;
    if (i < n) dinv[i] = rsqrtf((float)v + 1.0f);
    int s = v;
    #pragma unroll
    for (int off = 1; off < 64; off <<= 1) {
        int t = __shfl_up(s, off, 64);
        if (lane >= off) s += t;
    }
    if (lane == 63) wsum[wid] = s;
    __syncthreads();
    if (wid == 0 && lane < 16) {
        int ws = wsum[lane];
        #pragma unroll
        for (int off = 1; off < 16; off <<= 1) {
            int t = __shfl_up(ws, off, 64);
            if (lane >= off) ws += t;
        }
        wsum[lane] = ws;
        if (lane == 15) bsums[blockIdx.x] = ws;
    }
    __syncthreads();
    int wpre = (wid > 0) ? wsum[wid - 1] : 0;
    if (i < n) offsets[i] = wpre + s - v;
}

__global__ void scan_bsums(int* __restrict__ bsums, int nb) {
    __shared__ int wsum[16];
    int tid = threadIdx.x, lane = tid & 63, wid = tid >> 6;
    int v = (tid < nb) ? bsums[tid] : 0;
    int s = v;
    #pragma unroll
    for (int off = 1; off < 64; off <<= 1) {
        int t = __shfl_up(s, off, 64);
        if (lane >= off) s += t;
    }
    if (lane == 63) wsum[wid] = s;
    __syncthreads();
    if (wid == 0 && lane < 16) {
        int ws = wsum[lane];
        #pragma unroll
        for (int off = 1; off < 16; off <<= 1) {
            int t = __shfl_up(ws, off, 64);
            if (lane >= off) ws += t;
        }
        wsum[lane] = ws;
    }
    __syncthreads();
    int wpre = (wid > 0) ? wsum[wid - 1] : 0;
    if (tid < nb) bsums[tid] = wpre + s - v;
}

__global__ void scan_add(int* __restrict__ offsets, const int* __restrict__ bsums,
                         int n, int E) {
    int i = blockIdx.x * 1024 + threadIdx.x;
    if (i < n) offsets[i] += bsums[blockIdx.x];
    if (i == 0) offsets[n] = E;
}

// ---------- gemm1: x[N,128] @ W1[128,64] via MFMA bf16, f32 accum ----------
__global__ __launch_bounds__(256) void gemm1_mfma(
        const float* __restrict__ x, const float* __restrict__ W1,
        const float* __restrict__ dinv, ushort_t* __restrict__ xws_bf, int n) {
    __shared__ ushort_t Xs[64 * 136];      // padded row stride 136 (17408 B)
    __shared__ ushort_t Wl[16 * 64 * 8];   // [kblk][col][j] (16384 B)
    int tid = threadIdx.x;
    {
        const float4* Wv = reinterpret_cast<const float4*>(W1);  // 2048 float4
        #pragma unroll
        for (int p = 0; p < 8; ++p) {
            int idx = p * 256 + tid;
            float4 w = Wv[idx];
            int k = idx >> 4;            // 16 float4 per k-row (64 cols)
            int c0 = (idx & 15) * 4;
            ushort_t* d = &Wl[(k >> 3) * 512 + c0 * 8 + (k & 7)];
            d[0]  = f2bf(w.x);
            d[8]  = f2bf(w.y);
            d[16] = f2bf(w.z);
            d[24] = f2bf(w.w);
        }
    }
    int row0 = blockIdx.x * 64;
    {
        const float4* xv = reinterpret_cast<const float4*>(x + (size_t)row0 * C_IN);
        int maxv = min(64, n - row0) * (C_IN / 4);
        #pragma unroll
        for (int p = 0; p < 8; ++p) {
            int idx = p * 256 + tid;
            float4 v = (idx < maxv) ? xv[idx] : float4{0.f, 0.f, 0.f, 0.f};
            int row = idx >> 5, k4 = idx & 31;
            ushort4 pk;
            pk.x = f2bf(v.x); pk.y = f2bf(v.y); pk.z = f2bf(v.z); pk.w = f2bf(v.w);
            *reinterpret_cast<ushort4*>(&Xs[row * 136 + k4 * 4]) = pk;
        }
    }
    __syncthreads();
    int wid = tid >> 6, lane = tid & 63;
    int rbase = wid * 16;
    int l15 = lane & 15, kgrp = lane >> 4;
    f32x4 acc0 = {0.f, 0.f, 0.f, 0.f}, acc1 = acc0, acc2 = acc0, acc3 = acc0;
    #pragma unroll
    for (int kc = 0; kc < 4; ++kc) {
        bf16x8 a = *reinterpret_cast<const bf16x8*>(&Xs[(rbase + l15) * 136 + kc * 32 + kgrp * 8]);
        const ushort_t* wb = &Wl[(kc * 4 + kgrp) * 512 + l15 * 8];
        bf16x8 b0 = *reinterpret_cast<const bf16x8*>(wb);
        bf16x8 b1 = *reinterpret_cast<const bf16x8*>(wb + 128);
        bf16x8 b2 = *reinterpret_cast<const bf16x8*>(wb + 256);
        bf16x8 b3 = *reinterpret_cast<const bf16x8*>(wb + 384);
        acc0 = __builtin_amdgcn_mfma_f32_16x16x32_bf16(a, b0, acc0, 0, 0, 0);
        acc1 = __builtin_amdgcn_mfma_f32_16x16x32_bf16(a, b1, acc1, 0, 0, 0);
        acc2 = __builtin_amdgcn_mfma_f32_16x16x32_bf16(a, b2, acc2, 0, 0, 0);
        acc3 = __builtin_amdgcn_mfma_f32_16x16x32_bf16(a, b3, acc3, 0, 0, 0);
    }
    #pragma unroll
    for (int j = 0; j < 4; ++j) {
        int row = row0 + rbase + kgrp * 4 + j;
        if (row < n) {
            float di = dinv[row];
            ushort_t* o = &xws_bf[(size_t)row * C_HID + l15];
            o[0]  = f2bf(di * acc0[j]);
            o[16] = f2bf(di * acc1[j]);
            o[32] = f2bf(di * acc2[j]);
            o[48] = f2bf(di * acc3[j]);
        }
    }
}

// ---------- gemm2 (f32 VALU, LDS-tiled; h bf16 in, xws2 bf16 out) ----------

__global__ __launch_bounds__(256) void gemm2(
        const ushort_t* __restrict__ h_bf, const float* __restrict__ W2,
        const float* __restrict__ dinv, ushort_t* __restrict__ xws2_bf, int n) {
    __shared__ float Ws[C_HID * C_OUT];  // 8 KiB
    __shared__ float Hs[128 * C_HID];    // 32 KiB
    int tid = threadIdx.x;
    {
        const float4* Wv = reinterpret_cast<const float4*>(W2);
        float4* Wsv = reinterpret_cast<float4*>(Ws);
        #pragma unroll
        for (int p = 0; p < (C_HID * C_OUT / 4) / 256; ++p)
            Wsv[p * 256 + tid] = Wv[p * 256 + tid];
    }
    int row0 = blockIdx.x * 128;
    {
        const uint4* hv = reinterpret_cast<const uint4*>(h_bf + (size_t)row0 * C_HID);
        float4* Hsv = reinterpret_cast<float4*>(Hs);
        int maxe = min(128, n - row0) * (C_HID / 8);
        #pragma unroll
        for (int p = 0; p < 4; ++p) {
            int idx = p * 256 + tid;
            uint4 raw = (idx < maxe) ? hv[idx] : uint4{0u, 0u, 0u, 0u};
            float4 lo, hi;
            lo.x = bflo(raw.x); lo.y = bfhi(raw.x);
            lo.z = bflo(raw.y); lo.w = bfhi(raw.y);
            hi.x = bflo(raw.z); hi.y = bfhi(raw.z);
            hi.z = bflo(raw.w); hi.w = bfhi(raw.w);
            Hsv[idx * 2] = lo;
            Hsv[idx * 2 + 1] = hi;
        }
    }
    __syncthreads();
    int wid = tid >> 6, lane = tid & 63;
    int col = lane & 31, rh = lane >> 5;
    int rbase = wid * 32 + rh * 16;
    float acc[16];
    #pragma unroll
    for (int r = 0; r < 16; ++r) acc[r] = 0.f;
    const float4* Hsv = reinterpret_cast<const float4*>(Hs);
    #pragma unroll 2
    for (int k4 = 0; k4 < C_HID / 4; ++k4) {
        float w0 = Ws[(k4 * 4 + 0) * C_OUT + col];
        float w1 = Ws[(k4 * 4 + 1) * C_OUT + col];
        float w2 = Ws[(k4 * 4 + 2) * C_OUT + col];
        float w3 = Ws[(k4 * 4 + 3) * C_OUT + col];
        #pragma unroll
        for (int r = 0; r < 16; ++r) {
            float4 hv = Hsv[(rbase + r) * (C_HID / 4) + k4];
            acc[r] += hv.x * w0 + hv.y * w1 + hv.z * w2 + hv.w * w3;
        }
    }
    #pragma unroll
    for (int r = 0; r < 16; ++r) {
        int row = row0 + rbase + r;
        if (row < n) xws2_bf[(size_t)row * C_OUT + col] = f2bf(dinv[row] * acc[r]);
    }
}

// ---------- Aggregations: one node per half/quarter wave, no shuffles ----------

// agg1: half-wave (32 lanes x uint = 64 ch) owns one node; 8-deep gather unroll.
__global__ void agg1(const ushort_t* __restrict__ xws_bf, const float* __restrict__ dinv,
                     const int* __restrict__ offsets, const int* __restrict__ csr_src,
                     const float* __restrict__ b1, ushort_t* __restrict__ h_bf, int n) {
    int wid = threadIdx.x >> 6, lane = threadIdx.x & 63;
    int half = lane >> 5, c2 = lane & 31;
    const unsigned int* xu = reinterpret_cast<const unsigned int*>(xws_bf);
    float2 bb = *reinterpret_cast<const float2*>(&b1[2 * c2]);
    for (int base = (blockIdx.x * 4 + wid) * 2; base < n; base += gridDim.x * 8) {
        int i = base + half;
        if (i < n) {
            int beg = offsets[i], end = offsets[i + 1];
            float di = dinv[i];
            unsigned int sv = xu[(size_t)i * 32 + c2];     // self-loop term
            float a0 = bflo(sv), a1 = bfhi(sv);
            int k = beg;
            for (; k + 8 <= end; k += 8) {
                int s0 = csr_src[k + 0];
                int s1 = csr_src[k + 1];
                int s2 = csr_src[k + 2];
                int s3 = csr_src[k + 3];
                int s4 = csr_src[k + 4];
                int s5 = csr_src[k + 5];
                int s6 = csr_src[k + 6];
                int s7 = csr_src[k + 7];
                unsigned int v0 = xu[(size_t)s0 * 32 + c2];
                unsigned int v1 = xu[(size_t)s1 * 32 + c2];
                unsigned int v2 = xu[(size_t)s2 * 32 + c2];
                unsigned int v3 = xu[(size_t)s3 * 32 + c2];
                unsigned int v4 = xu[(size_t)s4 * 32 + c2];
                unsigned int v5 = xu[(size_t)s5 * 32 + c2];
                unsigned int v6 = xu[(size_t)s6 * 32 + c2];
                unsigned int v7 = xu[(size_t)s7 * 32 + c2];
                a0 += ((bflo(v0) + bflo(v1)) + (bflo(v2) + bflo(v3)))
                    + ((bflo(v4) + bflo(v5)) + (bflo(v6) + bflo(v7)));
                a1 += ((bfhi(v0) + bfhi(v1)) + (bfhi(v2) + bfhi(v3)))
                    + ((bfhi(v4) + bfhi(v5)) + (bfhi(v6) + bfhi(v7)));
            }
            for (; k + 4 <= end; k += 4) {
                int s0 = csr_src[k + 0];
                int s1 = csr_src[k + 1];
                int s2 = csr_src[k + 2];
                int s3 = csr_src[k + 3];
                unsigned int v0 = xu[(size_t)s0 * 32 + c2];
                unsigned int v1 = xu[(size_t)s1 * 32 + c2];
                unsigned int v2 = xu[(size_t)s2 * 32 + c2];
                unsigned int v3 = xu[(size_t)s3 * 32 + c2];
                a0 += (bflo(v0) + bflo(v1)) + (bflo(v2) + bflo(v3));
                a1 += (bfhi(v0) + bfhi(v1)) + (bfhi(v2) + bfhi(v3));
            }
            for (; k < end; ++k) {
                int s = csr_src[k];
                unsigned int v = xu[(size_t)s * 32 + c2];
                a0 += bflo(v); a1 += bfhi(v);
            }
            float r0 = fmaxf(di * a0 + bb.x, 0.f);
            float r1 = fmaxf(di * a1 + bb.y, 0.f);
            unsigned int pk = (unsigned int)f2bf(r0) | ((unsigned int)f2bf(r1) << 16);
            *reinterpret_cast<unsigned int*>(&h_bf[(size_t)i * C_HID + 2 * c2]) = pk;
        }
    }
}

// agg2: quarter-wave (16 lanes x uint = 32 ch) owns one node; 8-deep unroll.
__global__ void agg2(const ushort_t* __restrict__ xws2_bf, const float* __restrict__ dinv,
                     const int* __restrict__ offsets, const int* __restrict__ csr_src,
                     const float* __restrict__ b2, float* __restrict__ out, int n) {
    int wid = threadIdx.x >> 6, lane = threadIdx.x & 63;
    int q = lane >> 4, c2 = lane & 15;
    const unsigned int* xu = reinterpret_cast<const unsigned int*>(xws2_bf);
    float2 bb = *reinterpret_cast<const float2*>(&b2[2 * c2]);
    for (int base = (blockIdx.x * 4 + wid) * 4; base < n; base += gridDim.x * 16) {
        int i = base + q;
        if (i < n) {
            int beg = offsets[i], end = offsets[i + 1];
            float di = dinv[i];
            unsigned int sv = xu[(size_t)i * 16 + c2];
            float a0 = bflo(sv), a1 = bfhi(sv);
            int k = beg;
            for (; k + 8 <= end; k += 8) {
                int s0 = csr_src[k + 0];
                int s1 = csr_src[k + 1];
                int s2 = csr_src[k + 2];
                int s3 = csr_src[k + 3];
                int s4 = csr_src[k + 4];
                int s5 = csr_src[k + 5];
                int s6 = csr_src[k + 6];
                int s7 = csr_src[k + 7];
                unsigned int v0 = xu[(size_t)s0 * 16 + c2];
                unsigned int v1 = xu[(size_t)s1 * 16 + c2];
                unsigned int v2 = xu[(size_t)s2 * 16 + c2];
                unsigned int v3 = xu[(size_t)s3 * 16 + c2];
                unsigned int v4 = xu[(size_t)s4 * 16 + c2];
                unsigned int v5 = xu[(size_t)s5 * 16 + c2];
                unsigned int v6 = xu[(size_t)s6 * 16 + c2];
                unsigned int v7 = xu[(size_t)s7 * 16 + c2];
                a0 += ((bflo(v0) + bflo(v1)) + (bflo(v2) + bflo(v3)))
                    + ((bflo(v4) + bflo(v5)) + (bflo(v6) + bflo(v7)));
                a1 += ((bfhi(v0) + bfhi(v1)) + (bfhi(v2) + bfhi(v3)))
                    + ((bfhi(v4) + bfhi(v5)) + (bfhi(v6) + bfhi(v7)));
            }
            for (; k + 4 <= end; k += 4) {
                int s0 = csr_src[k + 0];
                int s1 = csr_src[k + 1];
                int s2 = csr_src[k + 2];
                int s3 = csr_src[k + 3];
                unsigned int v0 = xu[(size_t)s0 * 16 + c2];
                unsigned int v1 = xu[(size_t)s1 * 16 + c2];
                unsigned int v2 = xu[(size_t)s2 * 16 + c2];
                unsigned int v3 = xu[(size_t)s3 * 16 + c2];
                a0 += (bflo(v0) + bflo(v1)) + (bflo(v2) + bflo(v3));
                a1 += (bfhi(v0) + bfhi(v1)) + (bfhi(v2) + bfhi(v3));
            }
            for (; k < end; ++k) {
                int s = csr_src[k];
                unsigned int v = xu[(size_t)s * 16 + c2];
                a0 += bflo(v); a1 += bfhi(v);
            }
            float2 r;
            r.x = di * a0 + bb.x;
            r.y = di * a1 + bb.y;
            *reinterpret_cast<float2*>(&out[(size_t)i * C_OUT + 2 * c2]) = r;
        }
    }
}

extern "C" void kernel_launch(void* const* d_in, const int* in_sizes, int n_in,
                              void* d_out, int out_size, void* d_ws, size_t ws_size,
                              hipStream_t stream) {
    const float* x  = (const float*)d_in[0];
    const int*   ei = (const int*)d_in[1];
    const float* W1 = (const float*)d_in[2];
    const float* b1 = (const float*)d_in[3];
    const float* W2 = (const float*)d_in[4];
    const float* b2 = (const float*)d_in[5];
    float* out = (float*)d_out;

    const int N = in_sizes[0] / C_IN;      // 100000
    const int E = in_sizes[1] / 2;         // 1600000
    const int* src = ei;
    const int* dst = ei + E;

    const int NB = (N + BK_NODES - 1) >> BK_SHIFT;          // 98
    const int CAP = (2 * (E / NB) + 1023) & ~1023;          // 32768 (2x mean)

    char* ws = (char*)d_ws;
    size_t off = 0;
    auto alloc = [&](size_t bytes) { char* p = ws + off; off += (bytes + 255) & ~(size_t)255; return p; };
    ushort_t* xw_bf  = (ushort_t*)alloc((size_t)N * C_HID * 2);  // xws1, reused as xws2
    ushort_t* h_bf   = (ushort_t*)alloc((size_t)N * C_HID * 2);
    int*   deg     = (int*)alloc((size_t)N * 4);       // fallback only
    float* dinv    = (float*)alloc((size_t)N * 4);
    int*   offsets = (int*)alloc((size_t)(N + 1) * 4);
    int*   cursor  = (int*)alloc((size_t)N * 4);       // fallback only
    int*   csr_src = (int*)alloc((size_t)E * 4);
    int*   bsums   = (int*)alloc(4096);                // fallback only
    int*   bcur    = (int*)alloc((size_t)BK_MAXB * 4);
    int*   ebase   = (int*)alloc((size_t)(BK_MAXB + 1) * 4);
    unsigned int* bucketed = (unsigned int*)alloc((size_t)NB * CAP * 4);
    bool use_bucket = (off <= ws_size) && (NB <= BK_MAXB) && (N < (1 << 17));

    const int nb1024 = (N + 1023) / 1024;  // 98

    if (use_bucket) {
        hipMemsetAsync(bcur, 0, (size_t)NB * 4, stream);
        bucket_edges<<<(E + EPB - 1) / EPB, 256, 0, stream>>>(
            src, dst, bcur, bucketed, CAP, E, NB);
        scan_eb<<<1, 128, 0, stream>>>(bcur, ebase, offsets, CAP, NB, N);
        fill_csr_fused<<<NB, 1024, 0, stream>>>(bucketed, ebase, offsets, dinv,
                                                csr_src, CAP, N);
    } else {
        hipMemsetAsync(deg, 0, (size_t)N * 4, stream);
        count_deg<<<2048, 256, 0, stream>>>(dst, deg, E);
        scan_blocks<<<nb1024, 1024, 0, stream>>>(deg, offsets, bsums, dinv, N);
        scan_bsums<<<1, 1024, 0, stream>>>(bsums, nb1024);
        scan_add<<<nb1024, 1024, 0, stream>>>(offsets, bsums, N, E);
        hipMemcpyAsync(cursor, offsets, (size_t)N * 4, hipMemcpyDeviceToDevice, stream);
        fill_csr<<<2048, 256, 0, stream>>>(src, dst, cursor, csr_src, E);
    }

    gemm1_mfma<<<(N + 63) / 64, 256, 0, stream>>>(x, W1, dinv, xw_bf, N);
    agg1<<<2048, 256, 0, stream>>>(xw_bf, dinv, offsets, csr_src, b1, h_bf, N);
    gemm2<<<(N + 127) / 128, 256, 0, stream>>>(h_bf, W2, dinv, xw_bf, N);
    agg2<<<2048, 256, 0, stream>>>(xw_bf, dinv, offsets, csr_src, b2, out, N);
}

// Round 11
// 132.610 us; speedup vs baseline: 1.7592x; 1.1239x over previous
//
#include <hip/hip_runtime.h>
#include <hip/hip_bf16.h>

// GCN 2-layer: x[N,128] @ W1[128,64] -> agg(+relu) -> @ W2[64,32] -> agg -> out[N,32]
// CSR-by-dst via bucket counting sort (R4/R5), fused fill (R10). bf16
// intermediates (R6). gemm1 MFMA (R7). Half/quarter-wave aggs (R10).
// R11: gemm2 -> MFMA (h already bf16; W2 bf16 in LDS); bucket prefix inlined
// into fill_csr_fused (scan_eb launch removed); bcur zeroed by tiny kernel
// (rocclr fillBuffer dispatch removed). 7 dispatches total.

#define C_IN  128
#define C_HID 64
#define C_OUT 32
#define BK_SHIFT 10
#define BK_NODES (1 << BK_SHIFT)
#define BK_MAXB  128
#define EPB 2048   // edges per bucket_edges block

typedef unsigned short ushort_t;
typedef __attribute__((ext_vector_type(8))) short bf16x8;
typedef __attribute__((ext_vector_type(4))) float f32x4;

__device__ inline ushort_t f2bf(float f) {
    __hip_bfloat16 b = __float2bfloat16(f);   // RNE
    return *reinterpret_cast<ushort_t*>(&b);
}
__device__ inline float bflo(unsigned int v) { return __uint_as_float(v << 16); }
__device__ inline float bfhi(unsigned int v) { return __uint_as_float(v & 0xffff0000u); }

// ---------- CSR build ----------

__global__ void zero_bcur(int* __restrict__ bcur, int nb) {
    int i = threadIdx.x;
    if (i < nb) bcur[i] = 0;
}

// Phase A: partition edges into 1024-node dst buckets, bucket-major packed.
__global__ __launch_bounds__(256) void bucket_edges(
        const int* __restrict__ src, const int* __restrict__ dst,
        int* __restrict__ bcur, unsigned int* __restrict__ bucketed,
        int cap, int E, int nb) {
    __shared__ unsigned int stage[EPB];
    __shared__ unsigned char bkt[EPB];
    __shared__ int cnt[BK_MAXB];
    __shared__ int lofs[BK_MAXB];
    __shared__ int base[BK_MAXB];
    int tid = threadIdx.x;
    for (int i = tid; i < nb; i += 256) cnt[i] = 0;
    __syncthreads();
    int e0 = blockIdx.x * EPB;
    int myb[8]; int myr[8]; unsigned int mys[8];
    #pragma unroll
    for (int i = 0; i < 8; ++i) {
        int e = e0 + i * 256 + tid;
        if (e < E) {
            int d = dst[e];
            int s = src[e];
            int b = d >> BK_SHIFT;
            myb[i] = b;
            mys[i] = (unsigned int)s | ((unsigned int)(d & (BK_NODES - 1)) << 17);
            myr[i] = atomicAdd(&cnt[b], 1);
        } else myb[i] = -1;
    }
    __syncthreads();
    if (tid < 64) {
        int b0 = 2 * tid, b1 = 2 * tid + 1;
        int c0 = (b0 < nb) ? cnt[b0] : 0;
        int c1 = (b1 < nb) ? cnt[b1] : 0;
        int p = c0 + c1;
        int s = p;
        #pragma unroll
        for (int off = 1; off < 64; off <<= 1) {
            int t = __shfl_up(s, off, 64);
            if (tid >= off) s += t;
        }
        if (b0 < nb) lofs[b0] = s - p;
        if (b1 < nb) lofs[b1] = s - c1;
    }
    __syncthreads();
    #pragma unroll
    for (int i = 0; i < 8; ++i) {
        if (myb[i] >= 0) {
            int p = lofs[myb[i]] + myr[i];
            stage[p] = mys[i];
            bkt[p] = (unsigned char)myb[i];
        }
    }
    for (int i = tid; i < nb; i += 256)
        base[i] = atomicAdd(&bcur[i], cnt[i]);
    __syncthreads();
    int total = min(EPB, E - e0);
    for (int p = tid; p < total; p += 256) {
        int b = bkt[p];
        int di = base[b] + (p - lofs[b]);
        if (di < cap)
            bucketed[(size_t)b * cap + di] = stage[p];
    }
}

// Fused per-bucket: inlined bucket prefix (redundant per block, 98 ints, L2-hot)
// -> LDS degree histogram -> LDS scan -> offsets+dinv -> LDS-cursor csr fill.
__global__ __launch_bounds__(1024) void fill_csr_fused(
        const unsigned int* __restrict__ bucketed, const int* __restrict__ bcur,
        int* __restrict__ offsets, float* __restrict__ dinv,
        int* __restrict__ csr_src, int cap, int nb, int n) {
    __shared__ int hist[BK_NODES];
    __shared__ int wsum[16];
    __shared__ int sEb[BK_MAXB + 1];
    __shared__ int sW[2];
    int tid = threadIdx.x, lane = tid & 63, wid = tid >> 6;
    int b = blockIdx.x;
    // bucket prefix over bcur[0..nb) (nb <= 128), computed by first 2 waves
    int v128 = 0, s128 = 0;
    if (tid < 128) {
        v128 = (tid < nb) ? min(bcur[tid], cap) : 0;
        s128 = v128;
        #pragma unroll
        for (int off = 1; off < 64; off <<= 1) {
            int t = __shfl_up(s128, off, 64);
            if (lane >= off) s128 += t;
        }
        if (lane == 63) sW[wid] = s128;
    }
    __syncthreads();
    if (tid < 128) {
        int incl = s128 + ((wid == 1) ? sW[0] : 0);
        sEb[tid] = incl - v128;
        if (tid == nb - 1) sEb[nb] = incl;
    }
    hist[tid] = 0;
    __syncthreads();
    int eb = sEb[b];
    int cnt = sEb[b + 1] - eb;
    if (b == 0 && tid == 0) offsets[n] = sEb[nb];
    int node0 = b << BK_SHIFT;
    int nn = min(BK_NODES, n - node0);
    const unsigned int* bp = bucketed + (size_t)b * cap;
    for (int e = tid; e < cnt; e += 1024)
        atomicAdd(&hist[bp[e] >> 17], 1);
    __syncthreads();
    int v = hist[tid];
    int s = v;
    #pragma unroll
    for (int off = 1; off < 64; off <<= 1) {
        int t = __shfl_up(s, off, 64);
        if (lane >= off) s += t;
    }
    if (lane == 63) wsum[wid] = s;
    __syncthreads();
    if (wid == 0 && lane < 16) {
        int ws = wsum[lane];
        #pragma unroll
        for (int off = 1; off < 16; off <<= 1) {
            int t = __shfl_up(ws, off, 64);
            if (lane >= off) ws += t;
        }
        wsum[lane] = ws;
    }
    __syncthreads();
    int wpre = (wid > 0) ? wsum[wid - 1] : 0;
    int excl = wpre + s - v;           // exclusive degree prefix within bucket
    if (tid < nn) {
        offsets[node0 + tid] = eb + excl;
        dinv[node0 + tid] = rsqrtf((float)v + 1.0f);
    }
    __syncthreads();                   // all hist/wsum reads done
    hist[tid] = eb + excl;             // cursor
    __syncthreads();
    for (int e = tid; e < cnt; e += 1024) {
        unsigned int u = bp[e];
        int pos = atomicAdd(&hist[u >> 17], 1);
        csr_src[pos] = (int)(u & 0x1FFFFu);
    }
}

// ---- fallback path kernels (unused when workspace suffices) ----
__global__ void count_deg(const int* __restrict__ dst, int* __restrict__ deg, int E) {
    int idx = blockIdx.x * blockDim.x + threadIdx.x;
    int stride = gridDim.x * blockDim.x;
    for (int e = idx; e < E; e += stride)
        atomicAdd(&deg[dst[e]], 1);
}

__global__ void fill_csr(const int* __restrict__ src, const int* __restrict__ dst,
                         int* __restrict__ cursor, int* __restrict__ csr_src, int E) {
    int idx = blockIdx.x * blockDim.x + threadIdx.x;
    int stride = gridDim.x * blockDim.x;
    for (int e = idx; e < E; e += stride) {
        int pos = atomicAdd(&cursor[dst[e]], 1);
        csr_src[pos] = src[e];
    }
}

__global__ void scan_blocks(const int* __restrict__ deg, int* __restrict__ offsets,
                            int* __restrict__ bsums, float* __restrict__ dinv, int n) {
    __shared__ int wsum[16];
    int tid = threadIdx.x, lane = tid & 63, wid = tid >> 6;
    int i = blockIdx.x * 1024 + tid;
    int v = (i < n) ? deg[i] : 0;
    if (i < n) dinv[i] = rsqrtf((float)v + 1.0f);
    int s = v;
    #pragma unroll
    for (int off = 1; off < 64; off <<= 1) {
        int t = __shfl_up(s, off, 64);
        if (lane >= off) s += t;
    }
    if (lane == 63) wsum[wid] = s;
    __syncthreads();
    if (wid == 0 && lane < 16) {
        int ws = wsum[lane];
        #pragma unroll
        for (int off = 1; off < 16; off <<= 1) {
            int t = __shfl_up(ws, off, 64);
            if (lane >= off) ws += t;
        }
        wsum[lane] = ws;
        if (lane == 15) bsums[blockIdx.x] = ws;
    }
    __syncthreads();
    int wpre = (wid > 0) ? wsum[wid - 1] : 0;
    if (i < n) offsets[i] = wpre + s - v;
}

__global__ void scan_bsums(int* __restrict__ bsums, int nb) {
    __shared__ int wsum[16];
    int tid = threadIdx.x, lane = tid & 63, wid = tid >> 6;
    int v = (tid < nb) ? bsums[tid] : 0;
    int s = v;
    #pragma unroll
    for (int off = 1; off < 64; off <<= 1) {
        int t = __shfl_up(s, off, 64);
        if (lane >= off) s += t;
    }
    if (lane == 63) wsum[wid] = s;
    __syncthreads();
    if (wid == 0 && lane < 16) {
        int ws = wsum[lane];
        #pragma unroll
        for (int off = 1; off < 16; off <<= 1) {
            int t = __shfl_up(ws, off, 64);
            if (lane >= off) ws += t;
        }
        wsum[lane] = ws;
    }
    __syncthreads();
    int wpre = (wid > 0) ? wsum[wid - 1] : 0;
    if (tid < nb) bsums[tid] = wpre + s - v;
}

__global__ void scan_add(int* __restrict__ offsets, const int* __restrict__ bsums,
                         int n, int E) {
    int i = blockIdx.x * 1024 + threadIdx.x;
    if (i < n) offsets[i] += bsums[blockIdx.x];
    if (i == 0) offsets[n] = E;
}

// ---------- gemm1: x[N,128] @ W1[128,64] via MFMA bf16, f32 accum ----------
__global__ __launch_bounds__(256) void gemm1_mfma(
        const float* __restrict__ x, const float* __restrict__ W1,
        const float* __restrict__ dinv, ushort_t* __restrict__ xws_bf, int n) {
    __shared__ ushort_t Xs[64 * 136];      // padded row stride 136 (17408 B)
    __shared__ ushort_t Wl[16 * 64 * 8];   // [kblk][col][j] (16384 B)
    int tid = threadIdx.x;
    {
        const float4* Wv = reinterpret_cast<const float4*>(W1);  // 2048 float4
        #pragma unroll
        for (int p = 0; p < 8; ++p) {
            int idx = p * 256 + tid;
            float4 w = Wv[idx];
            int k = idx >> 4;            // 16 float4 per k-row (64 cols)
            int c0 = (idx & 15) * 4;
            ushort_t* d = &Wl[(k >> 3) * 512 + c0 * 8 + (k & 7)];
            d[0]  = f2bf(w.x);
            d[8]  = f2bf(w.y);
            d[16] = f2bf(w.z);
            d[24] = f2bf(w.w);
        }
    }
    int row0 = blockIdx.x * 64;
    {
        const float4* xv = reinterpret_cast<const float4*>(x + (size_t)row0 * C_IN);
        int maxv = min(64, n - row0) * (C_IN / 4);
        #pragma unroll
        for (int p = 0; p < 8; ++p) {
            int idx = p * 256 + tid;
            float4 v = (idx < maxv) ? xv[idx] : float4{0.f, 0.f, 0.f, 0.f};
            int row = idx >> 5, k4 = idx & 31;
            ushort4 pk;
            pk.x = f2bf(v.x); pk.y = f2bf(v.y); pk.z = f2bf(v.z); pk.w = f2bf(v.w);
            *reinterpret_cast<ushort4*>(&Xs[row * 136 + k4 * 4]) = pk;
        }
    }
    __syncthreads();
    int wid = tid >> 6, lane = tid & 63;
    int rbase = wid * 16;
    int l15 = lane & 15, kgrp = lane >> 4;
    f32x4 acc0 = {0.f, 0.f, 0.f, 0.f}, acc1 = acc0, acc2 = acc0, acc3 = acc0;
    #pragma unroll
    for (int kc = 0; kc < 4; ++kc) {
        bf16x8 a = *reinterpret_cast<const bf16x8*>(&Xs[(rbase + l15) * 136 + kc * 32 + kgrp * 8]);
        const ushort_t* wb = &Wl[(kc * 4 + kgrp) * 512 + l15 * 8];
        bf16x8 b0 = *reinterpret_cast<const bf16x8*>(wb);
        bf16x8 b1 = *reinterpret_cast<const bf16x8*>(wb + 128);
        bf16x8 b2 = *reinterpret_cast<const bf16x8*>(wb + 256);
        bf16x8 b3 = *reinterpret_cast<const bf16x8*>(wb + 384);
        acc0 = __builtin_amdgcn_mfma_f32_16x16x32_bf16(a, b0, acc0, 0, 0, 0);
        acc1 = __builtin_amdgcn_mfma_f32_16x16x32_bf16(a, b1, acc1, 0, 0, 0);
        acc2 = __builtin_amdgcn_mfma_f32_16x16x32_bf16(a, b2, acc2, 0, 0, 0);
        acc3 = __builtin_amdgcn_mfma_f32_16x16x32_bf16(a, b3, acc3, 0, 0, 0);
    }
    #pragma unroll
    for (int j = 0; j < 4; ++j) {
        int row = row0 + rbase + kgrp * 4 + j;
        if (row < n) {
            float di = dinv[row];
            ushort_t* o = &xws_bf[(size_t)row * C_HID + l15];
            o[0]  = f2bf(di * acc0[j]);
            o[16] = f2bf(di * acc1[j]);
            o[32] = f2bf(di * acc2[j]);
            o[48] = f2bf(di * acc3[j]);
        }
    }
}

// ---------- gemm2: h[N,64] @ W2[64,32] via MFMA bf16 (h already bf16) ----------
__global__ __launch_bounds__(256) void gemm2_mfma(
        const ushort_t* __restrict__ h_bf, const float* __restrict__ W2,
        const float* __restrict__ dinv, ushort_t* __restrict__ xws2_bf, int n) {
    __shared__ ushort_t Hs[64 * 72];       // padded stride 72 (9216 B)
    __shared__ ushort_t Wl[8 * 32 * 8];    // [kblk][col][j] (4096 B)
    int tid = threadIdx.x;
    {
        const float4* Wv = reinterpret_cast<const float4*>(W2);  // 512 float4
        #pragma unroll
        for (int p = 0; p < 2; ++p) {
            int idx = p * 256 + tid;
            float4 w = Wv[idx];
            int k = idx >> 3;            // 8 float4 per k-row (32 cols)
            int c0 = (idx & 7) * 4;
            ushort_t* d = &Wl[(k >> 3) * 256 + c0 * 8 + (k & 7)];
            d[0]  = f2bf(w.x);
            d[8]  = f2bf(w.y);
            d[16] = f2bf(w.z);
            d[24] = f2bf(w.w);
        }
    }
    int row0 = blockIdx.x * 64;
    {
        const uint4* hv = reinterpret_cast<const uint4*>(h_bf + (size_t)row0 * C_HID);
        int maxv = min(64, n - row0) * 8;  // uint4 per row
        #pragma unroll
        for (int p = 0; p < 2; ++p) {
            int idx = p * 256 + tid;
            uint4 v = (idx < maxv) ? hv[idx] : uint4{0u, 0u, 0u, 0u};
            int row = idx >> 3, c16 = idx & 7;
            *reinterpret_cast<uint4*>(&Hs[row * 72 + c16 * 8]) = v;
        }
    }
    __syncthreads();
    int wid = tid >> 6, lane = tid & 63;
    int rbase = wid * 16;
    int l15 = lane & 15, kgrp = lane >> 4;
    f32x4 acc0 = {0.f, 0.f, 0.f, 0.f}, acc1 = acc0;
    #pragma unroll
    for (int kc = 0; kc < 2; ++kc) {
        bf16x8 a = *reinterpret_cast<const bf16x8*>(&Hs[(rbase + l15) * 72 + kc * 32 + kgrp * 8]);
        const ushort_t* wb = &Wl[(kc * 4 + kgrp) * 256 + l15 * 8];
        bf16x8 b0 = *reinterpret_cast<const bf16x8*>(wb);
        bf16x8 b1 = *reinterpret_cast<const bf16x8*>(wb + 128);
        acc0 = __builtin_amdgcn_mfma_f32_16x16x32_bf16(a, b0, acc0, 0, 0, 0);
        acc1 = __builtin_amdgcn_mfma_f32_16x16x32_bf16(a, b1, acc1, 0, 0, 0);
    }
    #pragma unroll
    for (int j = 0; j < 4; ++j) {
        int row = row0 + rbase + kgrp * 4 + j;
        if (row < n) {
            float di = dinv[row];
            ushort_t* o = &xws2_bf[(size_t)row * C_OUT + l15];
            o[0]  = f2bf(di * acc0[j]);
            o[16] = f2bf(di * acc1[j]);
        }
    }
}

// ---------- Aggregations: one node per half/quarter wave, no shuffles ----------

// agg1: half-wave (32 lanes x uint = 64 ch) owns one node; 8-deep gather unroll.
__global__ void agg1(const ushort_t* __restrict__ xws_bf, const float* __restrict__ dinv,
                     const int* __restrict__ offsets, const int* __restrict__ csr_src,
                     const float* __restrict__ b1, ushort_t* __restrict__ h_bf, int n) {
    int wid = threadIdx.x >> 6, lane = threadIdx.x & 63;
    int half = lane >> 5, c2 = lane & 31;
    const unsigned int* xu = reinterpret_cast<const unsigned int*>(xws_bf);
    float2 bb = *reinterpret_cast<const float2*>(&b1[2 * c2]);
    for (int base = (blockIdx.x * 4 + wid) * 2; base < n; base += gridDim.x * 8) {
        int i = base + half;
        if (i < n) {
            int beg = offsets[i], end = offsets[i + 1];
            float di = dinv[i];
            unsigned int sv = xu[(size_t)i * 32 + c2];     // self-loop term
            float a0 = bflo(sv), a1 = bfhi(sv);
            int k = beg;
            for (; k + 8 <= end; k += 8) {
                int s0 = csr_src[k + 0];
                int s1 = csr_src[k + 1];
                int s2 = csr_src[k + 2];
                int s3 = csr_src[k + 3];
                int s4 = csr_src[k + 4];
                int s5 = csr_src[k + 5];
                int s6 = csr_src[k + 6];
                int s7 = csr_src[k + 7];
                unsigned int v0 = xu[(size_t)s0 * 32 + c2];
                unsigned int v1 = xu[(size_t)s1 * 32 + c2];
                unsigned int v2 = xu[(size_t)s2 * 32 + c2];
                unsigned int v3 = xu[(size_t)s3 * 32 + c2];
                unsigned int v4 = xu[(size_t)s4 * 32 + c2];
                unsigned int v5 = xu[(size_t)s5 * 32 + c2];
                unsigned int v6 = xu[(size_t)s6 * 32 + c2];
                unsigned int v7 = xu[(size_t)s7 * 32 + c2];
                a0 += ((bflo(v0) + bflo(v1)) + (bflo(v2) + bflo(v3)))
                    + ((bflo(v4) + bflo(v5)) + (bflo(v6) + bflo(v7)));
                a1 += ((bfhi(v0) + bfhi(v1)) + (bfhi(v2) + bfhi(v3)))
                    + ((bfhi(v4) + bfhi(v5)) + (bfhi(v6) + bfhi(v7)));
            }
            for (; k + 4 <= end; k += 4) {
                int s0 = csr_src[k + 0];
                int s1 = csr_src[k + 1];
                int s2 = csr_src[k + 2];
                int s3 = csr_src[k + 3];
                unsigned int v0 = xu[(size_t)s0 * 32 + c2];
                unsigned int v1 = xu[(size_t)s1 * 32 + c2];
                unsigned int v2 = xu[(size_t)s2 * 32 + c2];
                unsigned int v3 = xu[(size_t)s3 * 32 + c2];
                a0 += (bflo(v0) + bflo(v1)) + (bflo(v2) + bflo(v3));
                a1 += (bfhi(v0) + bfhi(v1)) + (bfhi(v2) + bfhi(v3));
            }
            for (; k < end; ++k) {
                int s = csr_src[k];
                unsigned int v = xu[(size_t)s * 32 + c2];
                a0 += bflo(v); a1 += bfhi(v);
            }
            float r0 = fmaxf(di * a0 + bb.x, 0.f);
            float r1 = fmaxf(di * a1 + bb.y, 0.f);
            unsigned int pk = (unsigned int)f2bf(r0) | ((unsigned int)f2bf(r1) << 16);
            *reinterpret_cast<unsigned int*>(&h_bf[(size_t)i * C_HID + 2 * c2]) = pk;
        }
    }
}

// agg2: quarter-wave (16 lanes x uint = 32 ch) owns one node; 8-deep unroll.
__global__ void agg2(const ushort_t* __restrict__ xws2_bf, const float* __restrict__ dinv,
                     const int* __restrict__ offsets, const int* __restrict__ csr_src,
                     const float* __restrict__ b2, float* __restrict__ out, int n) {
    int wid = threadIdx.x >> 6, lane = threadIdx.x & 63;
    int q = lane >> 4, c2 = lane & 15;
    const unsigned int* xu = reinterpret_cast<const unsigned int*>(xws2_bf);
    float2 bb = *reinterpret_cast<const float2*>(&b2[2 * c2]);
    for (int base = (blockIdx.x * 4 + wid) * 4; base < n; base += gridDim.x * 16) {
        int i = base + q;
        if (i < n) {
            int beg = offsets[i], end = offsets[i + 1];
            float di = dinv[i];
            unsigned int sv = xu[(size_t)i * 16 + c2];
            float a0 = bflo(sv), a1 = bfhi(sv);
            int k = beg;
            for (; k + 8 <= end; k += 8) {
                int s0 = csr_src[k + 0];
                int s1 = csr_src[k + 1];
                int s2 = csr_src[k + 2];
                int s3 = csr_src[k + 3];
                int s4 = csr_src[k + 4];
                int s5 = csr_src[k + 5];
                int s6 = csr_src[k + 6];
                int s7 = csr_src[k + 7];
                unsigned int v0 = xu[(size_t)s0 * 16 + c2];
                unsigned int v1 = xu[(size_t)s1 * 16 + c2];
                unsigned int v2 = xu[(size_t)s2 * 16 + c2];
                unsigned int v3 = xu[(size_t)s3 * 16 + c2];
                unsigned int v4 = xu[(size_t)s4 * 16 + c2];
                unsigned int v5 = xu[(size_t)s5 * 16 + c2];
                unsigned int v6 = xu[(size_t)s6 * 16 + c2];
                unsigned int v7 = xu[(size_t)s7 * 16 + c2];
                a0 += ((bflo(v0) + bflo(v1)) + (bflo(v2) + bflo(v3)))
                    + ((bflo(v4) + bflo(v5)) + (bflo(v6) + bflo(v7)));
                a1 += ((bfhi(v0) + bfhi(v1)) + (bfhi(v2) + bfhi(v3)))
                    + ((bfhi(v4) + bfhi(v5)) + (bfhi(v6) + bfhi(v7)));
            }
            for (; k + 4 <= end; k += 4) {
                int s0 = csr_src[k + 0];
                int s1 = csr_src[k + 1];
                int s2 = csr_src[k + 2];
                int s3 = csr_src[k + 3];
                unsigned int v0 = xu[(size_t)s0 * 16 + c2];
                unsigned int v1 = xu[(size_t)s1 * 16 + c2];
                unsigned int v2 = xu[(size_t)s2 * 16 + c2];
                unsigned int v3 = xu[(size_t)s3 * 16 + c2];
                a0 += (bflo(v0) + bflo(v1)) + (bflo(v2) + bflo(v3));
                a1 += (bfhi(v0) + bfhi(v1)) + (bfhi(v2) + bfhi(v3));
            }
            for (; k < end; ++k) {
                int s = csr_src[k];
                unsigned int v = xu[(size_t)s * 16 + c2];
                a0 += bflo(v); a1 += bfhi(v);
            }
            float2 r;
            r.x = di * a0 + bb.x;
            r.y = di * a1 + bb.y;
            *reinterpret_cast<float2*>(&out[(size_t)i * C_OUT + 2 * c2]) = r;
        }
    }
}

extern "C" void kernel_launch(void* const* d_in, const int* in_sizes, int n_in,
                              void* d_out, int out_size, void* d_ws, size_t ws_size,
                              hipStream_t stream) {
    const float* x  = (const float*)d_in[0];
    const int*   ei = (const int*)d_in[1];
    const float* W1 = (const float*)d_in[2];
    const float* b1 = (const float*)d_in[3];
    const float* W2 = (const float*)d_in[4];
    const float* b2 = (const float*)d_in[5];
    float* out = (float*)d_out;

    const int N = in_sizes[0] / C_IN;      // 100000
    const int E = in_sizes[1] / 2;         // 1600000
    const int* src = ei;
    const int* dst = ei + E;

    const int NB = (N + BK_NODES - 1) >> BK_SHIFT;          // 98
    const int CAP = (2 * (E / NB) + 1023) & ~1023;          // 32768 (2x mean)

    char* ws = (char*)d_ws;
    size_t off = 0;
    auto alloc = [&](size_t bytes) { char* p = ws + off; off += (bytes + 255) & ~(size_t)255; return p; };
    ushort_t* xw_bf  = (ushort_t*)alloc((size_t)N * C_HID * 2);  // xws1, reused as xws2
    ushort_t* h_bf   = (ushort_t*)alloc((size_t)N * C_HID * 2);
    int*   deg     = (int*)alloc((size_t)N * 4);       // fallback only
    float* dinv    = (float*)alloc((size_t)N * 4);
    int*   offsets = (int*)alloc((size_t)(N + 1) * 4);
    int*   cursor  = (int*)alloc((size_t)N * 4);       // fallback only
    int*   csr_src = (int*)alloc((size_t)E * 4);
    int*   bsums   = (int*)alloc(4096);                // fallback only
    int*   bcur    = (int*)alloc((size_t)BK_MAXB * 4);
    unsigned int* bucketed = (unsigned int*)alloc((size_t)NB * CAP * 4);
    bool use_bucket = (off <= ws_size) && (NB <= BK_MAXB) && (N < (1 << 17));

    const int nb1024 = (N + 1023) / 1024;  // 98

    if (use_bucket) {
        zero_bcur<<<1, 128, 0, stream>>>(bcur, NB);
        bucket_edges<<<(E + EPB - 1) / EPB, 256, 0, stream>>>(
            src, dst, bcur, bucketed, CAP, E, NB);
        fill_csr_fused<<<NB, 1024, 0, stream>>>(bucketed, bcur, offsets, dinv,
                                                csr_src, CAP, NB, N);
    } else {
        hipMemsetAsync(deg, 0, (size_t)N * 4, stream);
        count_deg<<<2048, 256, 0, stream>>>(dst, deg, E);
        scan_blocks<<<nb1024, 1024, 0, stream>>>(deg, offsets, bsums, dinv, N);
        scan_bsums<<<1, 1024, 0, stream>>>(bsums, nb1024);
        scan_add<<<nb1024, 1024, 0, stream>>>(offsets, bsums, N, E);
        hipMemcpyAsync(cursor, offsets, (size_t)N * 4, hipMemcpyDeviceToDevice, stream);
        fill_csr<<<2048, 256, 0, stream>>>(src, dst, cursor, csr_src, E);
    }

    gemm1_mfma<<<(N + 63) / 64, 256, 0, stream>>>(x, W1, dinv, xw_bf, N);
    agg1<<<2048, 256, 0, stream>>>(xw_bf, dinv, offsets, csr_src, b1, h_bf, N);
    gemm2_mfma<<<(N + 63) / 64, 256, 0, stream>>>(h_bf, W2, dinv, xw_bf, N);
    agg2<<<2048, 256, 0, stream>>>(xw_bf, dinv, offsets, csr_src, b2, out, N);
}